// Round 13
// baseline (192.873 us; speedup 1.0000x reference)
//
#include <hip/hip_runtime.h>
#include <hip/hip_bf16.h>
#include <math.h>

#define B_ 2
#define H_ 128
#define W_ 128
#define C_ 256
#define HID 64
#define PIX_PER (H_*W_)          // 16384
#define NPIX (B_*PIX_PER)        // 32768
#define K1STEPS 25               // 800 / 32 (fa 0-7, wb 8-15, diff 16-23, tail 24)
#define K3STEPS 18               // 576 / 32
#define SROW 258                 // LDS tap-row stride in u16 (1-dword bank skew)

using f32x4 = __attribute__((ext_vector_type(4))) float;
using s16x8 = __attribute__((ext_vector_type(8))) short;
using u16x2 = __attribute__((ext_vector_type(2))) unsigned short;
using u16x4 = __attribute__((ext_vector_type(4))) unsigned short;
using u16x8 = __attribute__((ext_vector_type(8))) unsigned short;

__device__ __forceinline__ float bf2f(unsigned short u) {
    return __uint_as_float(((unsigned)u) << 16);
}
__device__ __forceinline__ unsigned short f2bf(float f) {
    unsigned u = __float_as_uint(f);
    u += 0x7FFFu + ((u >> 16) & 1u);
    return (unsigned short)(u >> 16);
}
__device__ __forceinline__ float clean15(float v) {
    if (v != v) v = 0.f;
    return fminf(fmaxf(v, -1.5f), 1.5f);
}
__device__ __forceinline__ float clean01(float v) {
    if (v != v) v = 0.f;
    return fminf(fmaxf(v, 0.f), 1.f);
}

// ---------------- transpose NCHW -> NHWC bf16 (+ weight pack on z==4) ----------------
__global__ __launch_bounds__(256) void k_transpose(const float* __restrict__ A,
                                                   const float* __restrict__ Bm,
                                                   unsigned short* __restrict__ faT,
                                                   unsigned short* __restrict__ fbT,
                                                   const float* __restrict__ w1,
                                                   const float* __restrict__ w2,
                                                   const float* __restrict__ w3,
                                                   unsigned short* __restrict__ p1,
                                                   unsigned short* __restrict__ p2,
                                                   unsigned short* __restrict__ p3)
{
    if (blockIdx.z == 4) {              // weight-pack slice
        if (blockIdx.y != 0 || blockIdx.x >= 61) return;
        int t = blockIdx.x * 256 + threadIdx.x;
        if (t < 6400) {                                   // enc1: 25 ksteps
            int lane = t & 63, nt = (t >> 6) & 3, ks = t >> 8;
            int n = nt * 16 + (lane & 15);
            int kb = ks * 32 + 8 * (lane >> 4);
#pragma unroll
            for (int j = 0; j < 8; j++) {
                int k = kb + j;
                p1[(size_t)t * 8 + j] = (k < 780) ? f2bf(w1[(size_t)n * 780 + k]) : (unsigned short)0;
            }
        } else if (t < 6400 + 2 * 4608) {                 // enc2/enc3: 18 ksteps each
            int which = (t - 6400) / 4608;
            int idx = (t - 6400) % 4608;
            const float* w = which ? w3 : w2;
            unsigned short* p = which ? p3 : p2;
            int lane = idx & 63, nt = (idx >> 6) & 3, ks = idx >> 8;
            int n = nt * 16 + (lane & 15);
            int tap = ks >> 1;
            int ky = tap / 3, kx = tap % 3;
#pragma unroll
            for (int j = 0; j < 8; j++) {
                int c = (ks & 1) * 32 + 8 * (lane >> 4) + j;
                p[(size_t)idx * 8 + j] = f2bf(w[(((size_t)n * 64 + c) * 3 + ky) * 3 + kx]);
            }
        }
        return;
    }
    __shared__ float tile[32][33];
    int hw0 = blockIdx.x * 32;
    int c0  = blockIdx.y * 32;
    int z   = blockIdx.z;            // b*2 + which
    int b   = z >> 1;
    const float* src = (z & 1) ? Bm : A;
    unsigned short* dst = (z & 1) ? fbT : faT;
    int tx = threadIdx.x & 31, ty = threadIdx.x >> 5;   // 32 x 8
    const float* s = src + ((size_t)b * C_ + c0) * (size_t)PIX_PER + hw0;
#pragma unroll
    for (int i = 0; i < 32; i += 8) {
        float v = s[(size_t)(ty + i) * PIX_PER + tx];
        if (!isfinite(v)) v = 0.f;
        tile[ty + i][tx] = v;
    }
    __syncthreads();
    // write phase (race-checked, verified r9): thread t -> channel quad (t&7), hw row (t>>3)
    unsigned short* d = dst + ((size_t)b * PIX_PER + hw0) * C_ + c0;
    int pr = threadIdx.x & 7;
    int hw = threadIdx.x >> 3;
    u16x4 o;
#pragma unroll
    for (int j = 0; j < 4; j++) o[j] = f2bf(tile[4 * pr + j][hw]);
    *(u16x4*)(d + (size_t)hw * C_ + 4 * pr) = o;
}

// ---------------- sampling via per-pixel Gram MFMA, LDS-staged taps (r7, verified) ----------------
__global__ __launch_bounds__(256) void k_sample(const float* __restrict__ cw,
                                                const float* __restrict__ confp,
                                                const unsigned short* __restrict__ faT,
                                                const unsigned short* __restrict__ fbT,
                                                unsigned short* __restrict__ wbbuf,
                                                unsigned short* __restrict__ tail)
{
    __shared__ unsigned short S[4][17 * SROW];   // 35088 B: 16 taps + fa per wave
    __shared__ float CT[4][16 * 20 + 4];         // 5184 B: Gram C^T per wave
    int lane = threadIdx.x & 63;
    int wv = threadIdx.x >> 6;
    int wid = blockIdx.x * 4 + wv;
    int b = wid >> 14, y = (wid >> 7) & 127, x = wid & 127;

    float gx = clean15(cw[(size_t)wid * 2 + 0]);
    float gy = clean15(cw[(size_t)wid * 2 + 1]);
    float conf = clean01(confp[wid]);

    float pxu = (gx + 1.f) * 64.f - 0.5f;
    float pyu = (gy + 1.f) * 64.f - 0.5f;
    float x0f = floorf(pxu), y0f = floorf(pyu);
    float wx = pxu - x0f, wy = pyu - y0f;
    int x0 = (int)x0f, y0 = (int)y0f;
    int co[4], ro[4];
#pragma unroll
    for (int k = 0; k < 4; k++) {
        co[k] = min(max(x0 - 1 + k, 0), 127) << 8;
        ro[k] = min(max(y0 - 1 + k, 0), 127) << 15;
    }
    const unsigned short* fbP = fbT + ((size_t)b << 22);

    // stage: issue all 9 coalesced loads first, then LDS writes
    int h = lane >> 5, lo = lane & 31;
    u16x8 stg[8];
#pragma unroll
    for (int i = 0; i < 8; i++) {
        int rr = ro[i >> 1];
        int cc = h ? co[((i & 1) << 1) + 1] : co[(i & 1) << 1];
        stg[i] = *(const u16x8*)(fbP + rr + cc + lo * 8);
    }
    u16x8 stfa;
    if (h == 0) stfa = *(const u16x8*)(faT + (size_t)wid * C_ + lo * 8);

    unsigned short* Sw = &S[wv][0];
#pragma unroll
    for (int i = 0; i < 8; i++)
        *(u16x8*)(Sw + (2 * i + h) * SROW + lo * 8) = stg[i];
    if (h == 0) *(u16x8*)(Sw + 16 * SROW + lo * 8) = stfa;

    // Gram via 8 MFMAs, fragments from LDS
    int q = lane & 15;
    int tA = (q == 0) ? 16 : q - 1;
    int koff = (lane >> 4) * 8;
    const unsigned short* pA = Sw + tA * SROW + koff;
    const unsigned short* pB = Sw + q * SROW + koff;
    f32x4 acc = {0.f, 0.f, 0.f, 0.f};
#pragma unroll
    for (int ks = 0; ks < 8; ks++) {
        s16x8 av = *(const s16x8*)(pA + ks * 32);
        s16x8 bv = *(const s16x8*)(pB + ks * 32);
        acc = __builtin_amdgcn_mfma_f32_16x16x32_bf16(av, bv, acc, 0, 0, 0);
    }
    *(f32x4*)&CT[wv][q * 20 + (lane >> 4) * 4] = acc;

    // wb (center bilerp) + fa^2 / t15^2 partials, all from LDS
    float w00 = (1.f - wx) * (1.f - wy), w01 = wx * (1.f - wy);
    float w10 = (1.f - wx) * wy,         w11 = wx * wy;
    u16x4 v5  = *(const u16x4*)(Sw + 5 * SROW + lane * 4);
    u16x4 v6  = *(const u16x4*)(Sw + 6 * SROW + lane * 4);
    u16x4 v9  = *(const u16x4*)(Sw + 9 * SROW + lane * 4);
    u16x4 v10 = *(const u16x4*)(Sw + 10 * SROW + lane * 4);
    u16x4 v15 = *(const u16x4*)(Sw + 15 * SROW + lane * 4);
    u16x4 vfa = *(const u16x4*)(Sw + 16 * SROW + lane * 4);
    float fa2p = 0.f, t152p = 0.f;
    u16x4 wbo;
#pragma unroll
    for (int i = 0; i < 4; i++) {
        float s = w00 * bf2f(v5[i]) + w01 * bf2f(v6[i])
                + w10 * bf2f(v9[i]) + w11 * bf2f(v10[i]);
        wbo[i] = f2bf(s);
        float fv = bf2f(vfa[i]), tv = bf2f(v15[i]);
        fa2p  += fv * fv;
        t152p += tv * tv;
    }
    *(u16x4*)(wbbuf + (size_t)wid * C_ + lane * 4) = wbo;
#pragma unroll
    for (int m = 1; m < 64; m <<= 1) {
        fa2p  += __shfl_xor(fa2p, m);
        t152p += __shfl_xor(t152p, m);
    }

    // epilogue: lanes 0..31 assemble the 32-entry tail row
    if (lane < 32) {
        float outv = 0.f;
        if (lane == 0)      outv = gx - (((float)x + 0.5f) * 0.015625f - 1.f);
        else if (lane == 1) outv = gy - (((float)y + 0.5f) * 0.015625f - 1.f);
        else if (lane == 2) outv = conf;
        else if (lane < 12) {
            int j = lane - 3;
            int jd = j / 3, jm = j - jd * 3;
            int m00 = jd * 4 + jm;
            const float* Cw = &CT[wv][0];
            float D00 = Cw[m00 * 20], D01 = Cw[(m00 + 1) * 20];
            float D10 = Cw[(m00 + 4) * 20], D11 = Cw[(m00 + 5) * 20];
            float dot = w00 * D00 + w01 * D01 + w10 * D10 + w11 * D11;
#define GR(a, b) Cw[(b) * 20 + (a) + 1]
            float g11 = (j == 8) ? t152p : GR(m00 + 5, m00 + 5);
            float s2 = w00 * w00 * GR(m00, m00) + w01 * w01 * GR(m00 + 1, m00 + 1)
                     + w10 * w10 * GR(m00 + 4, m00 + 4) + w11 * w11 * g11
                     + 2.f * (w00 * w01 * GR(m00, m00 + 1) + w00 * w10 * GR(m00, m00 + 4)
                            + w00 * w11 * GR(m00, m00 + 5) + w01 * w10 * GR(m00 + 1, m00 + 4)
                            + w01 * w11 * GR(m00 + 1, m00 + 5) + w10 * w11 * GR(m00 + 4, m00 + 5));
#undef GR
            outv = dot * rsqrtf(fmaxf(fa2p, 1e-24f)) * rsqrtf(fmaxf(s2, 1e-24f));
        }
        tail[(size_t)wid * 32 + lane] = f2bf(outv);
    }
}

// ---- GN partial-stats epilogue for gemm1 (4-wave, per-block partials) ----
__device__ __forceinline__ void gn_epilogue(const f32x4 acc[4], float* lds,
                                            float* __restrict__ pbuf, int bid,
                                            int la, int lb, int wv)
{
    int d = la >> 3;
    int slot = wv * 32 + lb * 8 + (la & 7);
#pragma unroll
    for (int nt = 0; nt < 4; nt++) {
        float s  = acc[nt][0] + acc[nt][1] + acc[nt][2] + acc[nt][3];
        float s2 = acc[nt][0] * acc[nt][0] + acc[nt][1] * acc[nt][1]
                 + acc[nt][2] * acc[nt][2] + acc[nt][3] * acc[nt][3];
        int g = nt * 2 + d;
        lds[(g * 128 + slot) * 2 + 0] = s;
        lds[(g * 128 + slot) * 2 + 1] = s2;
    }
    __syncthreads();
    int tid = threadIdx.x;
    int g = tid >> 5, i = tid & 31;
    float s  = lds[(g * 128 + i) * 2]     + lds[(g * 128 + i + 32) * 2]
             + lds[(g * 128 + i + 64) * 2] + lds[(g * 128 + i + 96) * 2];
    float s2 = lds[(g * 128 + i) * 2 + 1]     + lds[(g * 128 + i + 32) * 2 + 1]
             + lds[(g * 128 + i + 64) * 2 + 1] + lds[(g * 128 + i + 96) * 2 + 1];
#pragma unroll
    for (int m = 1; m < 32; m <<= 1) { s += __shfl_xor(s, m); s2 += __shfl_xor(s2, m); }
    if (i == 0) {
        pbuf[(bid * 8 + g) * 2]     = s;
        pbuf[(bid * 8 + g) * 2 + 1] = s2;
    }
}

// ---------------- conv1x1 as MFMA GEMM, A assembled on the fly ----------------
__global__ __launch_bounds__(256) void k_gemm1(const unsigned short* __restrict__ faT,
                                               const unsigned short* __restrict__ wbbuf,
                                               const unsigned short* __restrict__ tail,
                                               const unsigned short* __restrict__ pack,
                                               unsigned short* __restrict__ hpre,
                                               float* __restrict__ pbuf)
{
    __shared__ float lds[8 * 128 * 2];
    int wave = (blockIdx.x * 256 + threadIdx.x) >> 6;
    int lane = threadIdx.x & 63;
    int la = lane & 15, lb = lane >> 4;
    int row = wave * 16 + la;
    const unsigned short* fa_row = faT   + (size_t)row * C_ + lb * 8;
    const unsigned short* wb_row = wbbuf + (size_t)row * C_ + lb * 8;
    f32x4 acc[4] = {{0,0,0,0},{0,0,0,0},{0,0,0,0},{0,0,0,0}};

#pragma unroll
    for (int ks = 0; ks < 8; ks++) {
        s16x8 a = *(const s16x8*)(fa_row + ks * 32);
#pragma unroll
        for (int nt = 0; nt < 4; nt++)
            acc[nt] = __builtin_amdgcn_mfma_f32_16x16x32_bf16(a,
                *(const s16x8*)(pack + ((size_t)(ks * 4 + nt) * 64 + lane) * 8), acc[nt], 0, 0, 0);
    }
#pragma unroll
    for (int ks = 0; ks < 8; ks++) {
        s16x8 a = *(const s16x8*)(wb_row + ks * 32);
#pragma unroll
        for (int nt = 0; nt < 4; nt++)
            acc[nt] = __builtin_amdgcn_mfma_f32_16x16x32_bf16(a,
                *(const s16x8*)(pack + ((size_t)((ks + 8) * 4 + nt) * 64 + lane) * 8), acc[nt], 0, 0, 0);
    }
#pragma unroll
    for (int ks = 0; ks < 8; ks++) {
        u16x8 av = *(const u16x8*)(fa_row + ks * 32);
        u16x8 bv = *(const u16x8*)(wb_row + ks * 32);
        s16x8 a;
#pragma unroll
        for (int j = 0; j < 8; j++)
            a[j] = (short)f2bf(fabsf(bf2f(av[j]) - bf2f(bv[j])));
#pragma unroll
        for (int nt = 0; nt < 4; nt++)
            acc[nt] = __builtin_amdgcn_mfma_f32_16x16x32_bf16(a,
                *(const s16x8*)(pack + ((size_t)((ks + 16) * 4 + nt) * 64 + lane) * 8), acc[nt], 0, 0, 0);
    }
    {
        s16x8 a = *(const s16x8*)(tail + (size_t)row * 32 + lb * 8);
#pragma unroll
        for (int nt = 0; nt < 4; nt++)
            acc[nt] = __builtin_amdgcn_mfma_f32_16x16x32_bf16(a,
                *(const s16x8*)(pack + ((size_t)(24 * 4 + nt) * 64 + lane) * 8), acc[nt], 0, 0, 0);
    }

    int orow = wave * 16 + lb * 4;
#pragma unroll
    for (int nt = 0; nt < 4; nt++)
#pragma unroll
        for (int r = 0; r < 4; r++)
            hpre[(size_t)(orow + r) * HID + nt * 16 + la] = f2bf(acc[nt][r]);

    gn_epilogue(acc, lds, pbuf, blockIdx.x, la, lb, (threadIdx.x >> 6));
}

// ------- fused GN + GELU + conv3x3, 8x4 tile, wave = 16px x 32ch -------
// 1024 blocks (b x 32ty x 16tx), 4 waves: rp = wv>>1 -> row pair, h = wv&1 ->
// channel half (nt in {2h, 2h+1}). Halo 10x6 staged through GN+GELU into LDS
// (zeros = zero-pad). GN partials: skip-bit-8 shuffle (r8-validated) + 128B fold.
__global__ __launch_bounds__(256) void k_convgn(const unsigned short* __restrict__ hin,
                                                const float* __restrict__ gamma,
                                                const float* __restrict__ beta,
                                                const float* __restrict__ pbin,
                                                int npbb,
                                                const unsigned short* __restrict__ pack,
                                                unsigned short* __restrict__ hout,
                                                float* __restrict__ pbout)
{
    __shared__ unsigned short T[8 * 60 * 8];    // [c8][slot][8ch] = 7680 B
    __shared__ float ep[4][4][2];
    __shared__ float sm[16];
    int tid = threadIdx.x;
    int bid = blockIdx.x;                        // 1024 = 2b x 32ty x 16tx
    int b = bid >> 9;
    int tile = bid & 511;
    int ty0 = (tile >> 4) << 2, tx0 = (tile & 15) << 3;

    // fold prev-layer GN stats (npbb partial-blocks per batch)
    {
        int g = tid >> 5, i = tid & 31;
        float s = 0.f, s2 = 0.f;
        for (int k = 0; k < (npbb >> 5); k++) {
            int pb = b * npbb + i + k * 32;
            s  += pbin[(pb * 8 + g) * 2];
            s2 += pbin[(pb * 8 + g) * 2 + 1];
        }
#pragma unroll
        for (int m = 1; m < 32; m <<= 1) { s += __shfl_xor(s, m); s2 += __shfl_xor(s2, m); }
        if (i == 0) {
            const float inv = 1.f / 131072.f;
            float mean = s * inv;
            float var = fmaxf(s2 * inv - mean * mean, 0.f);
            sm[g * 2] = mean;
            sm[g * 2 + 1] = rsqrtf(var + 1e-5f);
        }
    }
    __syncthreads();

    // stage 10x6 halo with GN+GELU: 60 slots x 8 ch-octets = 480 tasks
#pragma unroll
    for (int pass = 0; pass < 2; pass++) {
        int idx = pass * 256 + tid;
        if (idx < 480) {
            int c8 = idx & 7, slot = idx >> 3;
            int py = slot / 10, px = slot - py * 10;   // py 0..5, px 0..9
            int gy = ty0 + py - 1, gx = tx0 + px - 1;
            u16x8 o = {0, 0, 0, 0, 0, 0, 0, 0};
            if ((unsigned)gy < 128u && (unsigned)gx < 128u) {
                int gpix = (b << 14) + (gy << 7) + gx;
                u16x8 v = *(const u16x8*)(hin + (size_t)gpix * HID + c8 * 8);
                float mean = sm[c8 * 2], rstd = sm[c8 * 2 + 1];
#pragma unroll
                for (int i = 0; i < 8; i++) {
                    int c = c8 * 8 + i;
                    float xn = (bf2f(v[i]) - mean) * rstd * gamma[c] + beta[c];
                    o[i] = f2bf(0.5f * xn * (1.f + erff(xn * 0.70710678118654752f)));
                }
            }
            *(u16x8*)(&T[(c8 * 60 + slot) * 8]) = o;
        }
    }
    __syncthreads();

    // conv3x3: wave -> rows {2rp, 2rp+1}, channels nt in {2h, 2h+1}
    int lane = tid & 63, wv = tid >> 6;
    int rp = wv >> 1, hh = wv & 1;
    int la = lane & 15, lb = lane >> 4;
    int ay = la >> 3, ax = la & 7;
    f32x4 acc[2] = {{0,0,0,0},{0,0,0,0}};
#pragma unroll
    for (int ks = 0; ks < K3STEPS; ks++) {
        int tap = ks >> 1;
        int dy = tap / 3, dx = tap - dy * 3;
        int c8 = (ks & 1) * 4 + lb;
        int py = rp * 2 + ay + dy;              // 0..5
        int px = ax + dx;                       // 0..9
        s16x8 a = *(const s16x8*)(&T[(c8 * 60 + py * 10 + px) * 8]);
#pragma unroll
        for (int j = 0; j < 2; j++) {
            int nt = 2 * hh + j;
            acc[j] = __builtin_amdgcn_mfma_f32_16x16x32_bf16(a,
                *(const s16x8*)(pack + ((size_t)(ks * 4 + nt) * 64 + lane) * 8), acc[j], 0, 0, 0);
        }
    }

    // write pre-GN output
#pragma unroll
    for (int j = 0; j < 2; j++) {
        int nt = 2 * hh + j;
#pragma unroll
        for (int r = 0; r < 4; r++) {
            int po = lb * 4 + r;
            int yy = ty0 + rp * 2 + (po >> 3);
            int xx = tx0 + (po & 7);
            hout[((size_t)((b << 14) + (yy << 7) + xx)) * HID + nt * 16 + la] = f2bf(acc[j][r]);
        }
    }

    // GN partials: skip la-bit3 in the reduce (group split), fold 2 row-pairs
#pragma unroll
    for (int j = 0; j < 2; j++) {
        float s  = acc[j][0] + acc[j][1] + acc[j][2] + acc[j][3];
        float s2 = acc[j][0]*acc[j][0] + acc[j][1]*acc[j][1]
                 + acc[j][2]*acc[j][2] + acc[j][3]*acc[j][3];
#pragma unroll
        for (int m = 1; m < 64; m <<= 1) {
            if (m == 8) continue;
            s  += __shfl_xor(s, m);
            s2 += __shfl_xor(s2, m);
        }
        if (lane == 0 || lane == 8) {
            ep[wv][j * 2 + (lane >> 3)][0] = s;
            ep[wv][j * 2 + (lane >> 3)][1] = s2;
        }
    }
    __syncthreads();
    if (tid < 8) {
        int g = tid;                 // g = 4h + 2j + d; waves h and h+2 hold it
        int hx = g >> 2, gl = g & 3;
        pbout[(bid * 8 + g) * 2]     = ep[hx][gl][0] + ep[hx + 2][gl][0];
        pbout[(bid * 8 + g) * 2 + 1] = ep[hx][gl][1] + ep[hx + 2][gl][1];
    }
}

// ------- fused GN3 + GELU + delta/conf heads + epilogue (verified r11) -------
__global__ __launch_bounds__(256) void k_gnfinal(const unsigned short* __restrict__ hpre,
                                                 const float* __restrict__ gamma,
                                                 const float* __restrict__ beta,
                                                 const float* __restrict__ pbuf,
                                                 const float* __restrict__ cw,
                                                 const float* __restrict__ confp,
                                                 const float* __restrict__ dw,
                                                 const float* __restrict__ db,
                                                 const float* __restrict__ cwgt,
                                                 const float* __restrict__ cb,
                                                 float* __restrict__ out)
{
    __shared__ unsigned short hnT[100 * 68];   // 10x10 px, 64 ch + 4 pad (13.6 KB)
    __shared__ float wds[1154];
    __shared__ float wcs[577];
    __shared__ float sm[16];
    int tid = threadIdx.x;
    int bid = blockIdx.x;                       // 512 = 2 batches x 16x16 tiles
    int b = bid >> 8;
    int tile = bid & 255;
    int ty0 = (tile >> 4) << 3, tx0 = (tile & 15) << 3;

    for (int i = tid; i < 1152; i += 256) wds[i] = dw[i];
    for (int i = tid; i < 576; i += 256) wcs[i] = cwgt[i];
    if (tid == 0) { wds[1152] = db[0]; wds[1153] = db[1]; wcs[576] = cb[0]; }

    // GN stats fold (512 convgn-blocks per batch)
    {
        int g = tid >> 5, i = tid & 31;
        float s = 0.f, s2 = 0.f;
#pragma unroll
        for (int k = 0; k < 16; k++) {
            int pb = b * 512 + i + k * 32;
            s  += pbuf[(pb * 8 + g) * 2];
            s2 += pbuf[(pb * 8 + g) * 2 + 1];
        }
#pragma unroll
        for (int m = 1; m < 32; m <<= 1) { s += __shfl_xor(s, m); s2 += __shfl_xor(s2, m); }
        if (i == 0) {
            const float inv = 1.f / 131072.f;
            float mean = s * inv;
            float var = fmaxf(s2 * inv - mean * mean, 0.f);
            sm[g * 2] = mean;
            sm[g * 2 + 1] = rsqrtf(var + 1e-5f);
        }
    }
    __syncthreads();

    // load halo + GN + GELU into LDS: 100 slots x 8 ch-octets = 800 items
#pragma unroll
    for (int pass = 0; pass < 4; pass++) {
        int idx = pass * 256 + tid;
        if (idx < 800) {
            int slot = idx >> 3, c8 = idx & 7;
            int py = slot / 10, px = slot - py * 10;
            int gy = ty0 + py - 1, gx = tx0 + px - 1;
            u16x8 o = {0, 0, 0, 0, 0, 0, 0, 0};
            if ((unsigned)gy < 128u && (unsigned)gx < 128u) {
                int gpix = (b << 14) + (gy << 7) + gx;
                u16x8 v = *(const u16x8*)(hpre + (size_t)gpix * HID + c8 * 8);
                float mean = sm[c8 * 2], rstd = sm[c8 * 2 + 1];
#pragma unroll
                for (int i = 0; i < 8; i++) {
                    int c = c8 * 8 + i;
                    float xn = (bf2f(v[i]) - mean) * rstd * gamma[c] + beta[c];
                    float ge = 0.5f * xn * (1.f + erff(xn * 0.70710678118654752f));
                    o[i] = f2bf(ge);
                }
            }
            *(u16x8*)(&hnT[slot * 68 + c8 * 8]) = o;
        }
    }
    __syncthreads();

    // heads: px p = tid>>2 (8x8 interior), part = tid&3 (2 ch-octets each)
    int p = tid >> 2, part = tid & 3;
    int py = (p >> 3) + 1, px = (p & 7) + 1;
    float d0 = 0.f, d1 = 0.f, c0 = 0.f;
#pragma unroll
    for (int ky = 0; ky < 3; ky++)
#pragma unroll
        for (int kx = 0; kx < 3; kx++) {
            const unsigned short* hp = &hnT[((py + ky - 1) * 10 + (px + kx - 1)) * 68];
            int widx = ky * 3 + kx;
#pragma unroll
            for (int cc = 0; cc < 2; cc++) {
                int c8 = part * 2 + cc;
                u16x8 v = *(const u16x8*)(hp + c8 * 8);
#pragma unroll
                for (int i = 0; i < 8; i++) {
                    float f = bf2f(v[i]);
                    int c = c8 * 8 + i;
                    d0 += f * wds[c * 9 + widx];
                    d1 += f * wds[576 + c * 9 + widx];
                    c0 += f * wcs[c * 9 + widx];
                }
            }
        }
#pragma unroll
    for (int m = 1; m < 4; m <<= 1) {
        d0 += __shfl_xor(d0, m);
        d1 += __shfl_xor(d1, m);
        c0 += __shfl_xor(c0, m);
    }
    if (part == 0) {
        int pix = (b << 14) + ((ty0 + py - 1) << 7) + (tx0 + px - 1);
        d0 = tanhf(d0 + wds[1152]);
        d1 = tanhf(d1 + wds[1153]);
        c0 += wcs[576];

        float gx = clean15(cw[(size_t)pix * 2 + 0]);
        float gy = clean15(cw[(size_t)pix * 2 + 1]);
        float fwx = fminf(fmaxf(gx + d0 * 0.0625f, -1.5f), 1.5f);
        float fwy = fminf(fmaxf(gy + d1 * 0.0625f, -1.5f), 1.5f);

        float conf = clean01(confp[pix]);
        float pp = fminf(fmaxf(conf, 1e-4f), 1.f - 1e-4f);
        float bl = logf(pp) - log1pf(-pp);
        float rl = bl + 0.5f * c0;
        float rc = fminf(fmaxf(1.f / (1.f + expf(-rl)), 0.f), 1.f);

        out[(size_t)pix * 2 + 0] = fwx;
        out[(size_t)pix * 2 + 1] = fwy;
        out[(size_t)NPIX * 2 + pix] = rc;
        out[(size_t)NPIX * 2 + NPIX + pix] = rl;
    }
}

// ---------------- launcher ----------------
extern "C" void kernel_launch(void* const* d_in, const int* in_sizes, int n_in,
                              void* d_out, int out_size, void* d_ws, size_t ws_size,
                              hipStream_t stream)
{
    const float* feat_A = (const float*)d_in[0];
    const float* feat_B = (const float*)d_in[1];
    const float* cw     = (const float*)d_in[2];
    const float* conf   = (const float*)d_in[3];
    const float* w1     = (const float*)d_in[4];
    const float* g1     = (const float*)d_in[5];
    const float* b1     = (const float*)d_in[6];
    const float* w2     = (const float*)d_in[7];
    const float* g2     = (const float*)d_in[8];
    const float* b2     = (const float*)d_in[9];
    const float* w3     = (const float*)d_in[10];
    const float* g3     = (const float*)d_in[11];
    const float* b3     = (const float*)d_in[12];
    const float* dw     = (const float*)d_in[13];
    const float* db     = (const float*)d_in[14];
    const float* cwgt   = (const float*)d_in[15];
    const float* cb     = (const float*)d_in[16];
    float* out = (float*)d_out;

    char* w = (char*)d_ws;
    size_t o = 0;
    unsigned short* faT  = (unsigned short*)(w + o); o += (size_t)NPIX * C_ * 2;     // 16 MB
    unsigned short* fbT  = (unsigned short*)(w + o); o += (size_t)NPIX * C_ * 2;     // 16 MB
    unsigned short* wbb  = (unsigned short*)(w + o); o += (size_t)NPIX * C_ * 2;     // 16 MB
    unsigned short* tail = (unsigned short*)(w + o); o += (size_t)NPIX * 32 * 2;     // 2 MB
    unsigned short* hA   = (unsigned short*)(w + o); o += (size_t)NPIX * HID * 2;    // 4 MB
    unsigned short* hB   = (unsigned short*)(w + o); o += (size_t)NPIX * HID * 2;    // 4 MB
    unsigned short* p1   = (unsigned short*)(w + o); o += (size_t)K1STEPS * 4 * 64 * 8 * 2;
    unsigned short* p2   = (unsigned short*)(w + o); o += (size_t)K3STEPS * 4 * 64 * 8 * 2;
    unsigned short* p3   = (unsigned short*)(w + o); o += (size_t)K3STEPS * 4 * 64 * 8 * 2;
    float* pbuf1 = (float*)(w + o); o += 1024 * 8 * 2 * 4;
    float* pbuf2 = (float*)(w + o); o += 1024 * 8 * 2 * 4;
    float* pbuf3 = (float*)(w + o); o += 1024 * 8 * 2 * 4;

    k_transpose<<<dim3(PIX_PER / 32, C_ / 32, 5), 256, 0, stream>>>(feat_A, feat_B, faT, fbT,
                                                                    w1, w2, w3, p1, p2, p3);
    k_sample<<<NPIX / 4, 256, 0, stream>>>(cw, conf, faT, fbT, wbb, tail);

    k_gemm1<<<(NPIX / 16) / 4, 256, 0, stream>>>(faT, wbb, tail, p1, hA, pbuf1);
    k_convgn<<<1024, 256, 0, stream>>>(hA, g1, b1, pbuf1, 256, p2, hB, pbuf2);
    k_convgn<<<1024, 256, 0, stream>>>(hB, g2, b2, pbuf2, 512, p3, hA, pbuf3);
    k_gnfinal<<<512, 256, 0, stream>>>(hA, g3, b3, pbuf3, cw, conf,
                                       dw, db, cwgt, cb, out);
}

// Round 14
// 129.933 us; speedup vs baseline: 1.4844x; 1.4844x over previous
//
#include <hip/hip_runtime.h>
#include <hip/hip_bf16.h>
#include <math.h>

#define B_ 2
#define H_ 128
#define W_ 128
#define C_ 256
#define HID 64
#define PIX_PER (H_*W_)          // 16384
#define NPIX (B_*PIX_PER)        // 32768
#define K1STEPS 25               // 800 / 32 (fa 0-7, wb 8-15, diff 16-23, tail 24)
#define K3STEPS 18               // 576 / 32
#define SROW 264                 // LDS tap-row stride in u16 (528B = 16B-aligned; do NOT shrink)

using f32x4 = __attribute__((ext_vector_type(4))) float;
using s16x8 = __attribute__((ext_vector_type(8))) short;
using u16x2 = __attribute__((ext_vector_type(2))) unsigned short;
using u16x4 = __attribute__((ext_vector_type(4))) unsigned short;
using u16x8 = __attribute__((ext_vector_type(8))) unsigned short;

__device__ __forceinline__ float bf2f(unsigned short u) {
    return __uint_as_float(((unsigned)u) << 16);
}
__device__ __forceinline__ unsigned short f2bf(float f) {
    unsigned u = __float_as_uint(f);
    u += 0x7FFFu + ((u >> 16) & 1u);
    return (unsigned short)(u >> 16);
}
__device__ __forceinline__ float clean15(float v) {
    if (v != v) v = 0.f;
    return fminf(fmaxf(v, -1.5f), 1.5f);
}
__device__ __forceinline__ float clean01(float v) {
    if (v != v) v = 0.f;
    return fminf(fmaxf(v, 0.f), 1.f);
}

// ---------------- transpose NCHW -> NHWC bf16 (+ weight pack on z==4) ----------------
__global__ __launch_bounds__(256) void k_transpose(const float* __restrict__ A,
                                                   const float* __restrict__ Bm,
                                                   unsigned short* __restrict__ faT,
                                                   unsigned short* __restrict__ fbT,
                                                   const float* __restrict__ w1,
                                                   const float* __restrict__ w2,
                                                   const float* __restrict__ w3,
                                                   unsigned short* __restrict__ p1,
                                                   unsigned short* __restrict__ p2,
                                                   unsigned short* __restrict__ p3)
{
    if (blockIdx.z == 4) {              // weight-pack slice
        if (blockIdx.y != 0 || blockIdx.x >= 61) return;
        int t = blockIdx.x * 256 + threadIdx.x;
        if (t < 6400) {                                   // enc1: 25 ksteps
            int lane = t & 63, nt = (t >> 6) & 3, ks = t >> 8;
            int n = nt * 16 + (lane & 15);
            int kb = ks * 32 + 8 * (lane >> 4);
#pragma unroll
            for (int j = 0; j < 8; j++) {
                int k = kb + j;
                p1[(size_t)t * 8 + j] = (k < 780) ? f2bf(w1[(size_t)n * 780 + k]) : (unsigned short)0;
            }
        } else if (t < 6400 + 2 * 4608) {                 // enc2/enc3: 18 ksteps each
            int which = (t - 6400) / 4608;
            int idx = (t - 6400) % 4608;
            const float* w = which ? w3 : w2;
            unsigned short* p = which ? p3 : p2;
            int lane = idx & 63, nt = (idx >> 6) & 3, ks = idx >> 8;
            int n = nt * 16 + (lane & 15);
            int tap = ks >> 1;
            int ky = tap / 3, kx = tap % 3;
#pragma unroll
            for (int j = 0; j < 8; j++) {
                int c = (ks & 1) * 32 + 8 * (lane >> 4) + j;
                p[(size_t)idx * 8 + j] = f2bf(w[(((size_t)n * 64 + c) * 3 + ky) * 3 + kx]);
            }
        }
        return;
    }
    __shared__ float tile[32][33];
    int hw0 = blockIdx.x * 32;
    int c0  = blockIdx.y * 32;
    int z   = blockIdx.z;            // b*2 + which
    int b   = z >> 1;
    const float* src = (z & 1) ? Bm : A;
    unsigned short* dst = (z & 1) ? fbT : faT;
    int tx = threadIdx.x & 31, ty = threadIdx.x >> 5;   // 32 x 8
    const float* s = src + ((size_t)b * C_ + c0) * (size_t)PIX_PER + hw0;
#pragma unroll
    for (int i = 0; i < 32; i += 8) {
        float v = s[(size_t)(ty + i) * PIX_PER + tx];
        if (!isfinite(v)) v = 0.f;
        tile[ty + i][tx] = v;
    }
    __syncthreads();
    // write phase (race-checked, verified r9): thread t -> channel quad (t&7), hw row (t>>3)
    unsigned short* d = dst + ((size_t)b * PIX_PER + hw0) * C_ + c0;
    int pr = threadIdx.x & 7;
    int hw = threadIdx.x >> 3;
    u16x4 o;
#pragma unroll
    for (int j = 0; j < 4; j++) o[j] = f2bf(tile[4 * pr + j][hw]);
    *(u16x4*)(d + (size_t)hw * C_ + 4 * pr) = o;
}

// ---------------- sampling via per-pixel Gram MFMA, LDS-staged taps (r7, verified) ----------------
__global__ __launch_bounds__(256) void k_sample(const float* __restrict__ cw,
                                                const float* __restrict__ confp,
                                                const unsigned short* __restrict__ faT,
                                                const unsigned short* __restrict__ fbT,
                                                unsigned short* __restrict__ wbbuf,
                                                unsigned short* __restrict__ tail)
{
    __shared__ unsigned short S[4][17 * SROW];   // 35904 B: 16 taps + fa per wave
    __shared__ float CT[4][16 * 20 + 4];         // 5184 B: Gram C^T per wave
    int lane = threadIdx.x & 63;
    int wv = threadIdx.x >> 6;
    int wid = blockIdx.x * 4 + wv;
    int b = wid >> 14, y = (wid >> 7) & 127, x = wid & 127;

    float gx = clean15(cw[(size_t)wid * 2 + 0]);
    float gy = clean15(cw[(size_t)wid * 2 + 1]);
    float conf = clean01(confp[wid]);

    float pxu = (gx + 1.f) * 64.f - 0.5f;
    float pyu = (gy + 1.f) * 64.f - 0.5f;
    float x0f = floorf(pxu), y0f = floorf(pyu);
    float wx = pxu - x0f, wy = pyu - y0f;
    int x0 = (int)x0f, y0 = (int)y0f;
    int co[4], ro[4];
#pragma unroll
    for (int k = 0; k < 4; k++) {
        co[k] = min(max(x0 - 1 + k, 0), 127) << 8;
        ro[k] = min(max(y0 - 1 + k, 0), 127) << 15;
    }
    const unsigned short* fbP = fbT + ((size_t)b << 22);

    // stage: issue all 9 coalesced loads first, then LDS writes
    int h = lane >> 5, lo = lane & 31;
    u16x8 stg[8];
#pragma unroll
    for (int i = 0; i < 8; i++) {
        int rr = ro[i >> 1];
        int cc = h ? co[((i & 1) << 1) + 1] : co[(i & 1) << 1];
        stg[i] = *(const u16x8*)(fbP + rr + cc + lo * 8);
    }
    u16x8 stfa;
    if (h == 0) stfa = *(const u16x8*)(faT + (size_t)wid * C_ + lo * 8);

    unsigned short* Sw = &S[wv][0];
#pragma unroll
    for (int i = 0; i < 8; i++)
        *(u16x8*)(Sw + (2 * i + h) * SROW + lo * 8) = stg[i];
    if (h == 0) *(u16x8*)(Sw + 16 * SROW + lo * 8) = stfa;

    // Gram via 8 MFMAs, fragments from LDS
    int q = lane & 15;
    int tA = (q == 0) ? 16 : q - 1;
    int koff = (lane >> 4) * 8;
    const unsigned short* pA = Sw + tA * SROW + koff;
    const unsigned short* pB = Sw + q * SROW + koff;
    f32x4 acc = {0.f, 0.f, 0.f, 0.f};
#pragma unroll
    for (int ks = 0; ks < 8; ks++) {
        s16x8 av = *(const s16x8*)(pA + ks * 32);
        s16x8 bv = *(const s16x8*)(pB + ks * 32);
        acc = __builtin_amdgcn_mfma_f32_16x16x32_bf16(av, bv, acc, 0, 0, 0);
    }
    *(f32x4*)&CT[wv][q * 20 + (lane >> 4) * 4] = acc;

    // wb (center bilerp) + fa^2 / t15^2 partials, all from LDS
    float w00 = (1.f - wx) * (1.f - wy), w01 = wx * (1.f - wy);
    float w10 = (1.f - wx) * wy,         w11 = wx * wy;
    u16x4 v5  = *(const u16x4*)(Sw + 5 * SROW + lane * 4);
    u16x4 v6  = *(const u16x4*)(Sw + 6 * SROW + lane * 4);
    u16x4 v9  = *(const u16x4*)(Sw + 9 * SROW + lane * 4);
    u16x4 v10 = *(const u16x4*)(Sw + 10 * SROW + lane * 4);
    u16x4 v15 = *(const u16x4*)(Sw + 15 * SROW + lane * 4);
    u16x4 vfa = *(const u16x4*)(Sw + 16 * SROW + lane * 4);
    float fa2p = 0.f, t152p = 0.f;
    u16x4 wbo;
#pragma unroll
    for (int i = 0; i < 4; i++) {
        float s = w00 * bf2f(v5[i]) + w01 * bf2f(v6[i])
                + w10 * bf2f(v9[i]) + w11 * bf2f(v10[i]);
        wbo[i] = f2bf(s);
        float fv = bf2f(vfa[i]), tv = bf2f(v15[i]);
        fa2p  += fv * fv;
        t152p += tv * tv;
    }
    *(u16x4*)(wbbuf + (size_t)wid * C_ + lane * 4) = wbo;
#pragma unroll
    for (int m = 1; m < 64; m <<= 1) {
        fa2p  += __shfl_xor(fa2p, m);
        t152p += __shfl_xor(t152p, m);
    }

    // epilogue: lanes 0..31 assemble the 32-entry tail row
    if (lane < 32) {
        float outv = 0.f;
        if (lane == 0)      outv = gx - (((float)x + 0.5f) * 0.015625f - 1.f);
        else if (lane == 1) outv = gy - (((float)y + 0.5f) * 0.015625f - 1.f);
        else if (lane == 2) outv = conf;
        else if (lane < 12) {
            int j = lane - 3;
            int jd = j / 3, jm = j - jd * 3;
            int m00 = jd * 4 + jm;
            const float* Cw = &CT[wv][0];
            float D00 = Cw[m00 * 20], D01 = Cw[(m00 + 1) * 20];
            float D10 = Cw[(m00 + 4) * 20], D11 = Cw[(m00 + 5) * 20];
            float dot = w00 * D00 + w01 * D01 + w10 * D10 + w11 * D11;
#define GR(a, b) Cw[(b) * 20 + (a) + 1]
            float g11 = (j == 8) ? t152p : GR(m00 + 5, m00 + 5);
            float s2 = w00 * w00 * GR(m00, m00) + w01 * w01 * GR(m00 + 1, m00 + 1)
                     + w10 * w10 * GR(m00 + 4, m00 + 4) + w11 * w11 * g11
                     + 2.f * (w00 * w01 * GR(m00, m00 + 1) + w00 * w10 * GR(m00, m00 + 4)
                            + w00 * w11 * GR(m00, m00 + 5) + w01 * w10 * GR(m00 + 1, m00 + 4)
                            + w01 * w11 * GR(m00 + 1, m00 + 5) + w10 * w11 * GR(m00 + 4, m00 + 5));
#undef GR
            outv = dot * rsqrtf(fmaxf(fa2p, 1e-24f)) * rsqrtf(fmaxf(s2, 1e-24f));
        }
        tail[(size_t)wid * 32 + lane] = f2bf(outv);
    }
}

// ---- GN partial-stats epilogue for gemm1 (4-wave, per-block partials) ----
__device__ __forceinline__ void gn_epilogue(const f32x4 acc[4], float* lds,
                                            float* __restrict__ pbuf, int bid,
                                            int la, int lb, int wv)
{
    int d = la >> 3;
    int slot = wv * 32 + lb * 8 + (la & 7);
#pragma unroll
    for (int nt = 0; nt < 4; nt++) {
        float s  = acc[nt][0] + acc[nt][1] + acc[nt][2] + acc[nt][3];
        float s2 = acc[nt][0] * acc[nt][0] + acc[nt][1] * acc[nt][1]
                 + acc[nt][2] * acc[nt][2] + acc[nt][3] * acc[nt][3];
        int g = nt * 2 + d;
        lds[(g * 128 + slot) * 2 + 0] = s;
        lds[(g * 128 + slot) * 2 + 1] = s2;
    }
    __syncthreads();
    int tid = threadIdx.x;
    int g = tid >> 5, i = tid & 31;
    float s  = lds[(g * 128 + i) * 2]     + lds[(g * 128 + i + 32) * 2]
             + lds[(g * 128 + i + 64) * 2] + lds[(g * 128 + i + 96) * 2];
    float s2 = lds[(g * 128 + i) * 2 + 1]     + lds[(g * 128 + i + 32) * 2 + 1]
             + lds[(g * 128 + i + 64) * 2 + 1] + lds[(g * 128 + i + 96) * 2 + 1];
#pragma unroll
    for (int m = 1; m < 32; m <<= 1) { s += __shfl_xor(s, m); s2 += __shfl_xor(s2, m); }
    if (i == 0) {
        pbuf[(bid * 8 + g) * 2]     = s;
        pbuf[(bid * 8 + g) * 2 + 1] = s2;
    }
}

// ---------------- conv1x1 as MFMA GEMM, A assembled on the fly ----------------
__global__ __launch_bounds__(256) void k_gemm1(const unsigned short* __restrict__ faT,
                                               const unsigned short* __restrict__ wbbuf,
                                               const unsigned short* __restrict__ tail,
                                               const unsigned short* __restrict__ pack,
                                               unsigned short* __restrict__ hpre,
                                               float* __restrict__ pbuf)
{
    __shared__ float lds[8 * 128 * 2];
    int wave = (blockIdx.x * 256 + threadIdx.x) >> 6;
    int lane = threadIdx.x & 63;
    int la = lane & 15, lb = lane >> 4;
    int row = wave * 16 + la;
    const unsigned short* fa_row = faT   + (size_t)row * C_ + lb * 8;
    const unsigned short* wb_row = wbbuf + (size_t)row * C_ + lb * 8;
    f32x4 acc[4] = {{0,0,0,0},{0,0,0,0},{0,0,0,0},{0,0,0,0}};

#pragma unroll
    for (int ks = 0; ks < 8; ks++) {
        s16x8 a = *(const s16x8*)(fa_row + ks * 32);
#pragma unroll
        for (int nt = 0; nt < 4; nt++)
            acc[nt] = __builtin_amdgcn_mfma_f32_16x16x32_bf16(a,
                *(const s16x8*)(pack + ((size_t)(ks * 4 + nt) * 64 + lane) * 8), acc[nt], 0, 0, 0);
    }
#pragma unroll
    for (int ks = 0; ks < 8; ks++) {
        s16x8 a = *(const s16x8*)(wb_row + ks * 32);
#pragma unroll
        for (int nt = 0; nt < 4; nt++)
            acc[nt] = __builtin_amdgcn_mfma_f32_16x16x32_bf16(a,
                *(const s16x8*)(pack + ((size_t)((ks + 8) * 4 + nt) * 64 + lane) * 8), acc[nt], 0, 0, 0);
    }
#pragma unroll
    for (int ks = 0; ks < 8; ks++) {
        u16x8 av = *(const u16x8*)(fa_row + ks * 32);
        u16x8 bv = *(const u16x8*)(wb_row + ks * 32);
        s16x8 a;
#pragma unroll
        for (int j = 0; j < 8; j++)
            a[j] = (short)f2bf(fabsf(bf2f(av[j]) - bf2f(bv[j])));
#pragma unroll
        for (int nt = 0; nt < 4; nt++)
            acc[nt] = __builtin_amdgcn_mfma_f32_16x16x32_bf16(a,
                *(const s16x8*)(pack + ((size_t)((ks + 16) * 4 + nt) * 64 + lane) * 8), acc[nt], 0, 0, 0);
    }
    {
        s16x8 a = *(const s16x8*)(tail + (size_t)row * 32 + lb * 8);
#pragma unroll
        for (int nt = 0; nt < 4; nt++)
            acc[nt] = __builtin_amdgcn_mfma_f32_16x16x32_bf16(a,
                *(const s16x8*)(pack + ((size_t)(24 * 4 + nt) * 64 + lane) * 8), acc[nt], 0, 0, 0);
    }

    int orow = wave * 16 + lb * 4;
#pragma unroll
    for (int nt = 0; nt < 4; nt++)
#pragma unroll
        for (int r = 0; r < 4; r++)
            hpre[(size_t)(orow + r) * HID + nt * 16 + la] = f2bf(acc[nt][r]);

    gn_epilogue(acc, lds, pbuf, blockIdx.x, la, lb, (threadIdx.x >> 6));
}

// ------- fused GN + GELU + conv3x3, 8x4 tile, wave = 16px x 32ch (r13) -------
__global__ __launch_bounds__(256) void k_convgn(const unsigned short* __restrict__ hin,
                                                const float* __restrict__ gamma,
                                                const float* __restrict__ beta,
                                                const float* __restrict__ pbin,
                                                int npbb,
                                                const unsigned short* __restrict__ pack,
                                                unsigned short* __restrict__ hout,
                                                float* __restrict__ pbout)
{
    __shared__ unsigned short T[8 * 60 * 8];    // [c8][slot][8ch] = 7680 B
    __shared__ float ep[4][4][2];
    __shared__ float sm[16];
    int tid = threadIdx.x;
    int bid = blockIdx.x;                        // 1024 = 2b x 32ty x 16tx
    int b = bid >> 9;
    int tile = bid & 511;
    int ty0 = (tile >> 4) << 2, tx0 = (tile & 15) << 3;

    // fold prev-layer GN stats (npbb partial-blocks per batch)
    {
        int g = tid >> 5, i = tid & 31;
        float s = 0.f, s2 = 0.f;
        for (int k = 0; k < (npbb >> 5); k++) {
            int pb = b * npbb + i + k * 32;
            s  += pbin[(pb * 8 + g) * 2];
            s2 += pbin[(pb * 8 + g) * 2 + 1];
        }
#pragma unroll
        for (int m = 1; m < 32; m <<= 1) { s += __shfl_xor(s, m); s2 += __shfl_xor(s2, m); }
        if (i == 0) {
            const float inv = 1.f / 131072.f;
            float mean = s * inv;
            float var = fmaxf(s2 * inv - mean * mean, 0.f);
            sm[g * 2] = mean;
            sm[g * 2 + 1] = rsqrtf(var + 1e-5f);
        }
    }
    __syncthreads();

    // stage 10x6 halo with GN+GELU: 60 slots x 8 ch-octets = 480 tasks
#pragma unroll
    for (int pass = 0; pass < 2; pass++) {
        int idx = pass * 256 + tid;
        if (idx < 480) {
            int c8 = idx & 7, slot = idx >> 3;
            int py = slot / 10, px = slot - py * 10;   // py 0..5, px 0..9
            int gy = ty0 + py - 1, gx = tx0 + px - 1;
            u16x8 o = {0, 0, 0, 0, 0, 0, 0, 0};
            if ((unsigned)gy < 128u && (unsigned)gx < 128u) {
                int gpix = (b << 14) + (gy << 7) + gx;
                u16x8 v = *(const u16x8*)(hin + (size_t)gpix * HID + c8 * 8);
                float mean = sm[c8 * 2], rstd = sm[c8 * 2 + 1];
#pragma unroll
                for (int i = 0; i < 8; i++) {
                    int c = c8 * 8 + i;
                    float xn = (bf2f(v[i]) - mean) * rstd * gamma[c] + beta[c];
                    o[i] = f2bf(0.5f * xn * (1.f + erff(xn * 0.70710678118654752f)));
                }
            }
            *(u16x8*)(&T[(c8 * 60 + slot) * 8]) = o;
        }
    }
    __syncthreads();

    // conv3x3: wave -> rows {2rp, 2rp+1}, channels nt in {2h, 2h+1}
    int lane = tid & 63, wv = tid >> 6;
    int rp = wv >> 1, hh = wv & 1;
    int la = lane & 15, lb = lane >> 4;
    int ay = la >> 3, ax = la & 7;
    f32x4 acc[2] = {{0,0,0,0},{0,0,0,0}};
#pragma unroll
    for (int ks = 0; ks < K3STEPS; ks++) {
        int tap = ks >> 1;
        int dy = tap / 3, dx = tap - dy * 3;
        int c8 = (ks & 1) * 4 + lb;
        int py = rp * 2 + ay + dy;              // 0..5
        int px = ax + dx;                       // 0..9
        s16x8 a = *(const s16x8*)(&T[(c8 * 60 + py * 10 + px) * 8]);
#pragma unroll
        for (int j = 0; j < 2; j++) {
            int nt = 2 * hh + j;
            acc[j] = __builtin_amdgcn_mfma_f32_16x16x32_bf16(a,
                *(const s16x8*)(pack + ((size_t)(ks * 4 + nt) * 64 + lane) * 8), acc[j], 0, 0, 0);
        }
    }

    // write pre-GN output
#pragma unroll
    for (int j = 0; j < 2; j++) {
        int nt = 2 * hh + j;
#pragma unroll
        for (int r = 0; r < 4; r++) {
            int po = lb * 4 + r;
            int yy = ty0 + rp * 2 + (po >> 3);
            int xx = tx0 + (po & 7);
            hout[((size_t)((b << 14) + (yy << 7) + xx)) * HID + nt * 16 + la] = f2bf(acc[j][r]);
        }
    }

    // GN partials: skip la-bit3 in the reduce (group split), fold 2 row-pairs
#pragma unroll
    for (int j = 0; j < 2; j++) {
        float s  = acc[j][0] + acc[j][1] + acc[j][2] + acc[j][3];
        float s2 = acc[j][0]*acc[j][0] + acc[j][1]*acc[j][1]
                 + acc[j][2]*acc[j][2] + acc[j][3]*acc[j][3];
#pragma unroll
        for (int m = 1; m < 64; m <<= 1) {
            if (m == 8) continue;
            s  += __shfl_xor(s, m);
            s2 += __shfl_xor(s2, m);
        }
        if (lane == 0 || lane == 8) {
            ep[wv][j * 2 + (lane >> 3)][0] = s;
            ep[wv][j * 2 + (lane >> 3)][1] = s2;
        }
    }
    __syncthreads();
    if (tid < 8) {
        int g = tid;                 // g = 4h + 2j + d; waves h and h+2 hold it
        int hx = g >> 2, gl = g & 3;
        pbout[(bid * 8 + g) * 2]     = ep[hx][gl][0] + ep[hx + 2][gl][0];
        pbout[(bid * 8 + g) * 2 + 1] = ep[hx][gl][1] + ep[hx + 2][gl][1];
    }
}

// ------- fused GN3 + GELU + delta/conf heads + epilogue (verified r11) -------
__global__ __launch_bounds__(256) void k_gnfinal(const unsigned short* __restrict__ hpre,
                                                 const float* __restrict__ gamma,
                                                 const float* __restrict__ beta,
                                                 const float* __restrict__ pbuf,
                                                 const float* __restrict__ cw,
                                                 const float* __restrict__ confp,
                                                 const float* __restrict__ dw,
                                                 const float* __restrict__ db,
                                                 const float* __restrict__ cwgt,
                                                 const float* __restrict__ cb,
                                                 float* __restrict__ out)
{
    __shared__ unsigned short hnT[100 * 68];   // 10x10 px, 64 ch + 4 pad (13.6 KB)
    __shared__ float wds[1154];
    __shared__ float wcs[577];
    __shared__ float sm[16];
    int tid = threadIdx.x;
    int bid = blockIdx.x;                       // 512 = 2 batches x 16x16 tiles
    int b = bid >> 8;
    int tile = bid & 255;
    int ty0 = (tile >> 4) << 3, tx0 = (tile & 15) << 3;

    for (int i = tid; i < 1152; i += 256) wds[i] = dw[i];
    for (int i = tid; i < 576; i += 256) wcs[i] = cwgt[i];
    if (tid == 0) { wds[1152] = db[0]; wds[1153] = db[1]; wcs[576] = cb[0]; }

    // GN stats fold (512 convgn-blocks per batch)
    {
        int g = tid >> 5, i = tid & 31;
        float s = 0.f, s2 = 0.f;
#pragma unroll
        for (int k = 0; k < 16; k++) {
            int pb = b * 512 + i + k * 32;
            s  += pbuf[(pb * 8 + g) * 2];
            s2 += pbuf[(pb * 8 + g) * 2 + 1];
        }
#pragma unroll
        for (int m = 1; m < 32; m <<= 1) { s += __shfl_xor(s, m); s2 += __shfl_xor(s2, m); }
        if (i == 0) {
            const float inv = 1.f / 131072.f;
            float mean = s * inv;
            float var = fmaxf(s2 * inv - mean * mean, 0.f);
            sm[g * 2] = mean;
            sm[g * 2 + 1] = rsqrtf(var + 1e-5f);
        }
    }
    __syncthreads();

    // load halo + GN + GELU into LDS: 100 slots x 8 ch-octets = 800 items
#pragma unroll
    for (int pass = 0; pass < 4; pass++) {
        int idx = pass * 256 + tid;
        if (idx < 800) {
            int slot = idx >> 3, c8 = idx & 7;
            int py = slot / 10, px = slot - py * 10;
            int gy = ty0 + py - 1, gx = tx0 + px - 1;
            u16x8 o = {0, 0, 0, 0, 0, 0, 0, 0};
            if ((unsigned)gy < 128u && (unsigned)gx < 128u) {
                int gpix = (b << 14) + (gy << 7) + gx;
                u16x8 v = *(const u16x8*)(hpre + (size_t)gpix * HID + c8 * 8);
                float mean = sm[c8 * 2], rstd = sm[c8 * 2 + 1];
#pragma unroll
                for (int i = 0; i < 8; i++) {
                    int c = c8 * 8 + i;
                    float xn = (bf2f(v[i]) - mean) * rstd * gamma[c] + beta[c];
                    float ge = 0.5f * xn * (1.f + erff(xn * 0.70710678118654752f));
                    o[i] = f2bf(ge);
                }
            }
            *(u16x8*)(&hnT[slot * 68 + c8 * 8]) = o;
        }
    }
    __syncthreads();

    // heads: px p = tid>>2 (8x8 interior), part = tid&3 (2 ch-octets each)
    int p = tid >> 2, part = tid & 3;
    int py = (p >> 3) + 1, px = (p & 7) + 1;
    float d0 = 0.f, d1 = 0.f, c0 = 0.f;
#pragma unroll
    for (int ky = 0; ky < 3; ky++)
#pragma unroll
        for (int kx = 0; kx < 3; kx++) {
            const unsigned short* hp = &hnT[((py + ky - 1) * 10 + (px + kx - 1)) * 68];
            int widx = ky * 3 + kx;
#pragma unroll
            for (int cc = 0; cc < 2; cc++) {
                int c8 = part * 2 + cc;
                u16x8 v = *(const u16x8*)(hp + c8 * 8);
#pragma unroll
                for (int i = 0; i < 8; i++) {
                    float f = bf2f(v[i]);
                    int c = c8 * 8 + i;
                    d0 += f * wds[c * 9 + widx];
                    d1 += f * wds[576 + c * 9 + widx];
                    c0 += f * wcs[c * 9 + widx];
                }
            }
        }
#pragma unroll
    for (int m = 1; m < 4; m <<= 1) {
        d0 += __shfl_xor(d0, m);
        d1 += __shfl_xor(d1, m);
        c0 += __shfl_xor(c0, m);
    }
    if (part == 0) {
        int pix = (b << 14) + ((ty0 + py - 1) << 7) + (tx0 + px - 1);
        d0 = tanhf(d0 + wds[1152]);
        d1 = tanhf(d1 + wds[1153]);
        c0 += wcs[576];

        float gx = clean15(cw[(size_t)pix * 2 + 0]);
        float gy = clean15(cw[(size_t)pix * 2 + 1]);
        float fwx = fminf(fmaxf(gx + d0 * 0.0625f, -1.5f), 1.5f);
        float fwy = fminf(fmaxf(gy + d1 * 0.0625f, -1.5f), 1.5f);

        float conf = clean01(confp[pix]);
        float pp = fminf(fmaxf(conf, 1e-4f), 1.f - 1e-4f);
        float bl = logf(pp) - log1pf(-pp);
        float rl = bl + 0.5f * c0;
        float rc = fminf(fmaxf(1.f / (1.f + expf(-rl)), 0.f), 1.f);

        out[(size_t)pix * 2 + 0] = fwx;
        out[(size_t)pix * 2 + 1] = fwy;
        out[(size_t)NPIX * 2 + pix] = rc;
        out[(size_t)NPIX * 2 + NPIX + pix] = rl;
    }
}

// ---------------- launcher ----------------
extern "C" void kernel_launch(void* const* d_in, const int* in_sizes, int n_in,
                              void* d_out, int out_size, void* d_ws, size_t ws_size,
                              hipStream_t stream)
{
    const float* feat_A = (const float*)d_in[0];
    const float* feat_B = (const float*)d_in[1];
    const float* cw     = (const float*)d_in[2];
    const float* conf   = (const float*)d_in[3];
    const float* w1     = (const float*)d_in[4];
    const float* g1     = (const float*)d_in[5];
    const float* b1     = (const float*)d_in[6];
    const float* w2     = (const float*)d_in[7];
    const float* g2     = (const float*)d_in[8];
    const float* b2     = (const float*)d_in[9];
    const float* w3     = (const float*)d_in[10];
    const float* g3     = (const float*)d_in[11];
    const float* b3     = (const float*)d_in[12];
    const float* dw     = (const float*)d_in[13];
    const float* db     = (const float*)d_in[14];
    const float* cwgt   = (const float*)d_in[15];
    const float* cb     = (const float*)d_in[16];
    float* out = (float*)d_out;

    char* w = (char*)d_ws;
    size_t o = 0;
    unsigned short* faT  = (unsigned short*)(w + o); o += (size_t)NPIX * C_ * 2;     // 16 MB
    unsigned short* fbT  = (unsigned short*)(w + o); o += (size_t)NPIX * C_ * 2;     // 16 MB
    unsigned short* wbb  = (unsigned short*)(w + o); o += (size_t)NPIX * C_ * 2;     // 16 MB
    unsigned short* tail = (unsigned short*)(w + o); o += (size_t)NPIX * 32 * 2;     // 2 MB
    unsigned short* hA   = (unsigned short*)(w + o); o += (size_t)NPIX * HID * 2;    // 4 MB
    unsigned short* hB   = (unsigned short*)(w + o); o += (size_t)NPIX * HID * 2;    // 4 MB
    unsigned short* p1   = (unsigned short*)(w + o); o += (size_t)K1STEPS * 4 * 64 * 8 * 2;
    unsigned short* p2   = (unsigned short*)(w + o); o += (size_t)K3STEPS * 4 * 64 * 8 * 2;
    unsigned short* p3   = (unsigned short*)(w + o); o += (size_t)K3STEPS * 4 * 64 * 8 * 2;
    float* pbuf1 = (float*)(w + o); o += 1024 * 8 * 2 * 4;
    float* pbuf2 = (float*)(w + o); o += 1024 * 8 * 2 * 4;
    float* pbuf3 = (float*)(w + o); o += 1024 * 8 * 2 * 4;

    k_transpose<<<dim3(PIX_PER / 32, C_ / 32, 5), 256, 0, stream>>>(feat_A, feat_B, faT, fbT,
                                                                    w1, w2, w3, p1, p2, p3);
    k_sample<<<NPIX / 4, 256, 0, stream>>>(cw, conf, faT, fbT, wbb, tail);

    k_gemm1<<<(NPIX / 16) / 4, 256, 0, stream>>>(faT, wbb, tail, p1, hA, pbuf1);
    k_convgn<<<1024, 256, 0, stream>>>(hA, g1, b1, pbuf1, 256, p2, hB, pbuf2);
    k_convgn<<<1024, 256, 0, stream>>>(hB, g2, b2, pbuf2, 512, p3, hA, pbuf3);
    k_gnfinal<<<512, 256, 0, stream>>>(hA, g3, b3, pbuf3, cw, conf,
                                       dw, db, cwgt, cb, out);
}

// Round 15
// 126.163 us; speedup vs baseline: 1.5288x; 1.0299x over previous
//
#include <hip/hip_runtime.h>
#include <hip/hip_bf16.h>
#include <math.h>

#define B_ 2
#define H_ 128
#define W_ 128
#define C_ 256
#define HID 64
#define PIX_PER (H_*W_)          // 16384
#define NPIX (B_*PIX_PER)        // 32768
#define K1STEPS 25               // 800 / 32 (fa 0-7, wb 8-15, diff 16-23, tail 24)
#define K3STEPS 18               // 576 / 32
#define SROW 264                 // LDS tap-row stride in u16 (528B = 16B-aligned; do NOT shrink)

using f32x4 = __attribute__((ext_vector_type(4))) float;
using s16x8 = __attribute__((ext_vector_type(8))) short;
using u16x2 = __attribute__((ext_vector_type(2))) unsigned short;
using u16x4 = __attribute__((ext_vector_type(4))) unsigned short;
using u16x8 = __attribute__((ext_vector_type(8))) unsigned short;

__device__ __forceinline__ float bf2f(unsigned short u) {
    return __uint_as_float(((unsigned)u) << 16);
}
__device__ __forceinline__ unsigned short f2bf(float f) {
    unsigned u = __float_as_uint(f);
    u += 0x7FFFu + ((u >> 16) & 1u);
    return (unsigned short)(u >> 16);
}
__device__ __forceinline__ float clean15(float v) {
    if (v != v) v = 0.f;
    return fminf(fmaxf(v, -1.5f), 1.5f);
}
__device__ __forceinline__ float clean01(float v) {
    if (v != v) v = 0.f;
    return fminf(fmaxf(v, 0.f), 1.f);
}

// ---------------- transpose NCHW -> NHWC bf16 (+ weight pack on z==4) ----------------
__global__ __launch_bounds__(256) void k_transpose(const float* __restrict__ A,
                                                   const float* __restrict__ Bm,
                                                   unsigned short* __restrict__ faT,
                                                   unsigned short* __restrict__ fbT,
                                                   const float* __restrict__ w1,
                                                   const float* __restrict__ w2,
                                                   const float* __restrict__ w3,
                                                   unsigned short* __restrict__ p1,
                                                   unsigned short* __restrict__ p2,
                                                   unsigned short* __restrict__ p3)
{
    if (blockIdx.z == 4) {              // weight-pack slice
        if (blockIdx.y != 0 || blockIdx.x >= 61) return;
        int t = blockIdx.x * 256 + threadIdx.x;
        if (t < 6400) {                                   // enc1: 25 ksteps
            int lane = t & 63, nt = (t >> 6) & 3, ks = t >> 8;
            int n = nt * 16 + (lane & 15);
            int kb = ks * 32 + 8 * (lane >> 4);
#pragma unroll
            for (int j = 0; j < 8; j++) {
                int k = kb + j;
                p1[(size_t)t * 8 + j] = (k < 780) ? f2bf(w1[(size_t)n * 780 + k]) : (unsigned short)0;
            }
        } else if (t < 6400 + 2 * 4608) {                 // enc2/enc3: 18 ksteps each
            int which = (t - 6400) / 4608;
            int idx = (t - 6400) % 4608;
            const float* w = which ? w3 : w2;
            unsigned short* p = which ? p3 : p2;
            int lane = idx & 63, nt = (idx >> 6) & 3, ks = idx >> 8;
            int n = nt * 16 + (lane & 15);
            int tap = ks >> 1;
            int ky = tap / 3, kx = tap % 3;
#pragma unroll
            for (int j = 0; j < 8; j++) {
                int c = (ks & 1) * 32 + 8 * (lane >> 4) + j;
                p[(size_t)idx * 8 + j] = f2bf(w[(((size_t)n * 64 + c) * 3 + ky) * 3 + kx]);
            }
        }
        return;
    }
    __shared__ float tile[32][33];
    int hw0 = blockIdx.x * 32;
    int c0  = blockIdx.y * 32;
    int z   = blockIdx.z;            // b*2 + which
    int b   = z >> 1;
    const float* src = (z & 1) ? Bm : A;
    unsigned short* dst = (z & 1) ? fbT : faT;
    int tx = threadIdx.x & 31, ty = threadIdx.x >> 5;   // 32 x 8
    const float* s = src + ((size_t)b * C_ + c0) * (size_t)PIX_PER + hw0;
#pragma unroll
    for (int i = 0; i < 32; i += 8) {
        float v = s[(size_t)(ty + i) * PIX_PER + tx];
        if (!isfinite(v)) v = 0.f;
        tile[ty + i][tx] = v;
    }
    __syncthreads();
    // write phase (race-checked, verified r9): thread t -> channel quad (t&7), hw row (t>>3)
    unsigned short* d = dst + ((size_t)b * PIX_PER + hw0) * C_ + c0;
    int pr = threadIdx.x & 7;
    int hw = threadIdx.x >> 3;
    u16x4 o;
#pragma unroll
    for (int j = 0; j < 4; j++) o[j] = f2bf(tile[4 * pr + j][hw]);
    *(u16x4*)(d + (size_t)hw * C_ + 4 * pr) = o;
}

// ---------------- sampling via per-pixel Gram MFMA, LDS-staged taps (r7, verified) ----------------
__global__ __launch_bounds__(256) void k_sample(const float* __restrict__ cw,
                                                const float* __restrict__ confp,
                                                const unsigned short* __restrict__ faT,
                                                const unsigned short* __restrict__ fbT,
                                                unsigned short* __restrict__ wbbuf,
                                                unsigned short* __restrict__ tail)
{
    __shared__ unsigned short S[4][17 * SROW];   // 35904 B: 16 taps + fa per wave
    __shared__ float CT[4][16 * 20 + 4];         // 5184 B: Gram C^T per wave
    int lane = threadIdx.x & 63;
    int wv = threadIdx.x >> 6;
    int wid = blockIdx.x * 4 + wv;
    int b = wid >> 14, y = (wid >> 7) & 127, x = wid & 127;

    float gx = clean15(cw[(size_t)wid * 2 + 0]);
    float gy = clean15(cw[(size_t)wid * 2 + 1]);
    float conf = clean01(confp[wid]);

    float pxu = (gx + 1.f) * 64.f - 0.5f;
    float pyu = (gy + 1.f) * 64.f - 0.5f;
    float x0f = floorf(pxu), y0f = floorf(pyu);
    float wx = pxu - x0f, wy = pyu - y0f;
    int x0 = (int)x0f, y0 = (int)y0f;
    int co[4], ro[4];
#pragma unroll
    for (int k = 0; k < 4; k++) {
        co[k] = min(max(x0 - 1 + k, 0), 127) << 8;
        ro[k] = min(max(y0 - 1 + k, 0), 127) << 15;
    }
    const unsigned short* fbP = fbT + ((size_t)b << 22);

    // stage: issue all 9 coalesced loads first, then LDS writes
    int h = lane >> 5, lo = lane & 31;
    u16x8 stg[8];
#pragma unroll
    for (int i = 0; i < 8; i++) {
        int rr = ro[i >> 1];
        int cc = h ? co[((i & 1) << 1) + 1] : co[(i & 1) << 1];
        stg[i] = *(const u16x8*)(fbP + rr + cc + lo * 8);
    }
    u16x8 stfa;
    if (h == 0) stfa = *(const u16x8*)(faT + (size_t)wid * C_ + lo * 8);

    unsigned short* Sw = &S[wv][0];
#pragma unroll
    for (int i = 0; i < 8; i++)
        *(u16x8*)(Sw + (2 * i + h) * SROW + lo * 8) = stg[i];
    if (h == 0) *(u16x8*)(Sw + 16 * SROW + lo * 8) = stfa;

    // Gram via 8 MFMAs, fragments from LDS
    int q = lane & 15;
    int tA = (q == 0) ? 16 : q - 1;
    int koff = (lane >> 4) * 8;
    const unsigned short* pA = Sw + tA * SROW + koff;
    const unsigned short* pB = Sw + q * SROW + koff;
    f32x4 acc = {0.f, 0.f, 0.f, 0.f};
#pragma unroll
    for (int ks = 0; ks < 8; ks++) {
        s16x8 av = *(const s16x8*)(pA + ks * 32);
        s16x8 bv = *(const s16x8*)(pB + ks * 32);
        acc = __builtin_amdgcn_mfma_f32_16x16x32_bf16(av, bv, acc, 0, 0, 0);
    }
    *(f32x4*)&CT[wv][q * 20 + (lane >> 4) * 4] = acc;

    // wb (center bilerp) + fa^2 / t15^2 partials, all from LDS
    float w00 = (1.f - wx) * (1.f - wy), w01 = wx * (1.f - wy);
    float w10 = (1.f - wx) * wy,         w11 = wx * wy;
    u16x4 v5  = *(const u16x4*)(Sw + 5 * SROW + lane * 4);
    u16x4 v6  = *(const u16x4*)(Sw + 6 * SROW + lane * 4);
    u16x4 v9  = *(const u16x4*)(Sw + 9 * SROW + lane * 4);
    u16x4 v10 = *(const u16x4*)(Sw + 10 * SROW + lane * 4);
    u16x4 v15 = *(const u16x4*)(Sw + 15 * SROW + lane * 4);
    u16x4 vfa = *(const u16x4*)(Sw + 16 * SROW + lane * 4);
    float fa2p = 0.f, t152p = 0.f;
    u16x4 wbo;
#pragma unroll
    for (int i = 0; i < 4; i++) {
        float s = w00 * bf2f(v5[i]) + w01 * bf2f(v6[i])
                + w10 * bf2f(v9[i]) + w11 * bf2f(v10[i]);
        wbo[i] = f2bf(s);
        float fv = bf2f(vfa[i]), tv = bf2f(v15[i]);
        fa2p  += fv * fv;
        t152p += tv * tv;
    }
    *(u16x4*)(wbbuf + (size_t)wid * C_ + lane * 4) = wbo;
#pragma unroll
    for (int m = 1; m < 64; m <<= 1) {
        fa2p  += __shfl_xor(fa2p, m);
        t152p += __shfl_xor(t152p, m);
    }

    // epilogue: lanes 0..31 assemble the 32-entry tail row
    if (lane < 32) {
        float outv = 0.f;
        if (lane == 0)      outv = gx - (((float)x + 0.5f) * 0.015625f - 1.f);
        else if (lane == 1) outv = gy - (((float)y + 0.5f) * 0.015625f - 1.f);
        else if (lane == 2) outv = conf;
        else if (lane < 12) {
            int j = lane - 3;
            int jd = j / 3, jm = j - jd * 3;
            int m00 = jd * 4 + jm;
            const float* Cw = &CT[wv][0];
            float D00 = Cw[m00 * 20], D01 = Cw[(m00 + 1) * 20];
            float D10 = Cw[(m00 + 4) * 20], D11 = Cw[(m00 + 5) * 20];
            float dot = w00 * D00 + w01 * D01 + w10 * D10 + w11 * D11;
#define GR(a, b) Cw[(b) * 20 + (a) + 1]
            float g11 = (j == 8) ? t152p : GR(m00 + 5, m00 + 5);
            float s2 = w00 * w00 * GR(m00, m00) + w01 * w01 * GR(m00 + 1, m00 + 1)
                     + w10 * w10 * GR(m00 + 4, m00 + 4) + w11 * w11 * g11
                     + 2.f * (w00 * w01 * GR(m00, m00 + 1) + w00 * w10 * GR(m00, m00 + 4)
                            + w00 * w11 * GR(m00, m00 + 5) + w01 * w10 * GR(m00 + 1, m00 + 4)
                            + w01 * w11 * GR(m00 + 1, m00 + 5) + w10 * w11 * GR(m00 + 4, m00 + 5));
#undef GR
            outv = dot * rsqrtf(fmaxf(fa2p, 1e-24f)) * rsqrtf(fmaxf(s2, 1e-24f));
        }
        tail[(size_t)wid * 32 + lane] = f2bf(outv);
    }
}

// ---- GN partial-stats epilogue shared by gemm1/convgn (per-block partials) ----
__device__ __forceinline__ void gn_epilogue(const f32x4 acc[4], float* lds,
                                            float* __restrict__ pbuf, int bid,
                                            int la, int lb, int wv)
{
    int d = la >> 3;
    int slot = wv * 32 + lb * 8 + (la & 7);
#pragma unroll
    for (int nt = 0; nt < 4; nt++) {
        float s  = acc[nt][0] + acc[nt][1] + acc[nt][2] + acc[nt][3];
        float s2 = acc[nt][0] * acc[nt][0] + acc[nt][1] * acc[nt][1]
                 + acc[nt][2] * acc[nt][2] + acc[nt][3] * acc[nt][3];
        int g = nt * 2 + d;
        lds[(g * 128 + slot) * 2 + 0] = s;
        lds[(g * 128 + slot) * 2 + 1] = s2;
    }
    __syncthreads();
    int tid = threadIdx.x;
    int g = tid >> 5, i = tid & 31;
    float s  = lds[(g * 128 + i) * 2]     + lds[(g * 128 + i + 32) * 2]
             + lds[(g * 128 + i + 64) * 2] + lds[(g * 128 + i + 96) * 2];
    float s2 = lds[(g * 128 + i) * 2 + 1]     + lds[(g * 128 + i + 32) * 2 + 1]
             + lds[(g * 128 + i + 64) * 2 + 1] + lds[(g * 128 + i + 96) * 2 + 1];
#pragma unroll
    for (int m = 1; m < 32; m <<= 1) { s += __shfl_xor(s, m); s2 += __shfl_xor(s2, m); }
    if (i == 0) {
        pbuf[(bid * 8 + g) * 2]     = s;
        pbuf[(bid * 8 + g) * 2 + 1] = s2;
    }
}

// ---------------- conv1x1 as MFMA GEMM, A assembled on the fly ----------------
__global__ __launch_bounds__(256) void k_gemm1(const unsigned short* __restrict__ faT,
                                               const unsigned short* __restrict__ wbbuf,
                                               const unsigned short* __restrict__ tail,
                                               const unsigned short* __restrict__ pack,
                                               unsigned short* __restrict__ hpre,
                                               float* __restrict__ pbuf)
{
    __shared__ float lds[8 * 128 * 2];
    int wave = (blockIdx.x * 256 + threadIdx.x) >> 6;
    int lane = threadIdx.x & 63;
    int la = lane & 15, lb = lane >> 4;
    int row = wave * 16 + la;
    const unsigned short* fa_row = faT   + (size_t)row * C_ + lb * 8;
    const unsigned short* wb_row = wbbuf + (size_t)row * C_ + lb * 8;
    f32x4 acc[4] = {{0,0,0,0},{0,0,0,0},{0,0,0,0},{0,0,0,0}};

#pragma unroll
    for (int ks = 0; ks < 8; ks++) {
        s16x8 a = *(const s16x8*)(fa_row + ks * 32);
#pragma unroll
        for (int nt = 0; nt < 4; nt++)
            acc[nt] = __builtin_amdgcn_mfma_f32_16x16x32_bf16(a,
                *(const s16x8*)(pack + ((size_t)(ks * 4 + nt) * 64 + lane) * 8), acc[nt], 0, 0, 0);
    }
#pragma unroll
    for (int ks = 0; ks < 8; ks++) {
        s16x8 a = *(const s16x8*)(wb_row + ks * 32);
#pragma unroll
        for (int nt = 0; nt < 4; nt++)
            acc[nt] = __builtin_amdgcn_mfma_f32_16x16x32_bf16(a,
                *(const s16x8*)(pack + ((size_t)((ks + 8) * 4 + nt) * 64 + lane) * 8), acc[nt], 0, 0, 0);
    }
#pragma unroll
    for (int ks = 0; ks < 8; ks++) {
        u16x8 av = *(const u16x8*)(fa_row + ks * 32);
        u16x8 bv = *(const u16x8*)(wb_row + ks * 32);
        s16x8 a;
#pragma unroll
        for (int j = 0; j < 8; j++)
            a[j] = (short)f2bf(fabsf(bf2f(av[j]) - bf2f(bv[j])));
#pragma unroll
        for (int nt = 0; nt < 4; nt++)
            acc[nt] = __builtin_amdgcn_mfma_f32_16x16x32_bf16(a,
                *(const s16x8*)(pack + ((size_t)((ks + 16) * 4 + nt) * 64 + lane) * 8), acc[nt], 0, 0, 0);
    }
    {
        s16x8 a = *(const s16x8*)(tail + (size_t)row * 32 + lb * 8);
#pragma unroll
        for (int nt = 0; nt < 4; nt++)
            acc[nt] = __builtin_amdgcn_mfma_f32_16x16x32_bf16(a,
                *(const s16x8*)(pack + ((size_t)(24 * 4 + nt) * 64 + lane) * 8), acc[nt], 0, 0, 0);
    }

    int orow = wave * 16 + lb * 4;
#pragma unroll
    for (int nt = 0; nt < 4; nt++)
#pragma unroll
        for (int r = 0; r < 4; r++)
            hpre[(size_t)(orow + r) * HID + nt * 16 + la] = f2bf(acc[nt][r]);

    gn_epilogue(acc, lds, pbuf, blockIdx.x, la, lb, (threadIdx.x >> 6));
}

// ------- fused GN + GELU + conv3x3 (r12-verified): 8x8 tile per block -------
__global__ __launch_bounds__(256) void k_convgn(const unsigned short* __restrict__ hin,
                                                const float* __restrict__ gamma,
                                                const float* __restrict__ beta,
                                                const float* __restrict__ pbin,
                                                const unsigned short* __restrict__ pack,
                                                unsigned short* __restrict__ hout,
                                                float* __restrict__ pbout)
{
    __shared__ unsigned short T[8 * 100 * 8];   // [c8][py*10+px][8ch] = 12800 B
    __shared__ float eplds[8 * 128 * 2];        // 8 KB
    __shared__ float sm[16];
    int tid = threadIdx.x;
    int bid = blockIdx.x;                        // 512 = 2 batches x 16x16 tiles
    int b = bid >> 8;
    int tile = bid & 255;
    int ty0 = (tile >> 4) << 3, tx0 = (tile & 15) << 3;

    // fold prev-layer GN stats (256 partial-blocks per batch)
    {
        int g = tid >> 5, i = tid & 31;
        float s = 0.f, s2 = 0.f;
#pragma unroll
        for (int k = 0; k < 8; k++) {
            int pb = b * 256 + i + k * 32;
            s  += pbin[(pb * 8 + g) * 2];
            s2 += pbin[(pb * 8 + g) * 2 + 1];
        }
#pragma unroll
        for (int m = 1; m < 32; m <<= 1) { s += __shfl_xor(s, m); s2 += __shfl_xor(s2, m); }
        if (i == 0) {
            const float inv = 1.f / 131072.f;
            float mean = s * inv;
            float var = fmaxf(s2 * inv - mean * mean, 0.f);
            sm[g * 2] = mean;
            sm[g * 2 + 1] = rsqrtf(var + 1e-5f);
        }
    }
    __syncthreads();

    // stage 10x10 halo with GN+GELU: 100 slots x 8 ch-octets = 800 tasks
#pragma unroll
    for (int pass = 0; pass < 4; pass++) {
        int idx = pass * 256 + tid;
        if (idx < 800) {
            int c8 = idx & 7, slot = idx >> 3;
            int py = slot / 10, px = slot - py * 10;
            int gy = ty0 + py - 1, gx = tx0 + px - 1;
            u16x8 o = {0, 0, 0, 0, 0, 0, 0, 0};
            if ((unsigned)gy < 128u && (unsigned)gx < 128u) {
                int gpix = (b << 14) + (gy << 7) + gx;
                u16x8 v = *(const u16x8*)(hin + (size_t)gpix * HID + c8 * 8);
                float mean = sm[c8 * 2], rstd = sm[c8 * 2 + 1];
#pragma unroll
                for (int i = 0; i < 8; i++) {
                    int c = c8 * 8 + i;
                    float xn = (bf2f(v[i]) - mean) * rstd * gamma[c] + beta[c];
                    o[i] = f2bf(0.5f * xn * (1.f + erff(xn * 0.70710678118654752f)));
                }
            }
            *(u16x8*)(&T[(c8 * 100 + slot) * 8]) = o;
        }
    }
    __syncthreads();

    // conv3x3: wave wv -> output rows {2wv, 2wv+1} of the 8x8 tile
    int lane = tid & 63, wv = tid >> 6;
    int la = lane & 15, lb = lane >> 4;
    int ay = la >> 3, ax = la & 7;              // A-row la -> (row-pair offset, x)
    f32x4 acc[4] = {{0,0,0,0},{0,0,0,0},{0,0,0,0},{0,0,0,0}};
#pragma unroll
    for (int ks = 0; ks < K3STEPS; ks++) {
        int tap = ks >> 1;
        int dy = tap / 3, dx = tap - dy * 3;
        int c8 = (ks & 1) * 4 + lb;
        int py = wv * 2 + ay + dy;
        int px = ax + dx;
        s16x8 a = *(const s16x8*)(&T[(c8 * 100 + py * 10 + px) * 8]);
#pragma unroll
        for (int nt = 0; nt < 4; nt++)
            acc[nt] = __builtin_amdgcn_mfma_f32_16x16x32_bf16(a,
                *(const s16x8*)(pack + ((size_t)(ks * 4 + nt) * 64 + lane) * 8), acc[nt], 0, 0, 0);
    }

    // write pre-GN output: C row = px_off = lb*4+r -> (y = +po>>3, x = po&7)
#pragma unroll
    for (int nt = 0; nt < 4; nt++)
#pragma unroll
        for (int r = 0; r < 4; r++) {
            int po = lb * 4 + r;
            int yy = ty0 + wv * 2 + (po >> 3);
            int xx = tx0 + (po & 7);
            hout[((size_t)((b << 14) + (yy << 7) + xx)) * HID + nt * 16 + la] = f2bf(acc[nt][r]);
        }

    gn_epilogue(acc, eplds, pbout, bid, la, lb, wv);
}

// ------- fused GN3 + GELU + delta/conf heads + epilogue (verified r11) -------
__global__ __launch_bounds__(256) void k_gnfinal(const unsigned short* __restrict__ hpre,
                                                 const float* __restrict__ gamma,
                                                 const float* __restrict__ beta,
                                                 const float* __restrict__ pbuf,
                                                 const float* __restrict__ cw,
                                                 const float* __restrict__ confp,
                                                 const float* __restrict__ dw,
                                                 const float* __restrict__ db,
                                                 const float* __restrict__ cwgt,
                                                 const float* __restrict__ cb,
                                                 float* __restrict__ out)
{
    __shared__ unsigned short hnT[100 * 68];   // 10x10 px, 64 ch + 4 pad (13.6 KB)
    __shared__ float wds[1154];
    __shared__ float wcs[577];
    __shared__ float sm[16];
    int tid = threadIdx.x;
    int bid = blockIdx.x;                       // 512 = 2 batches x 16x16 tiles
    int b = bid >> 8;
    int tile = bid & 255;
    int ty0 = (tile >> 4) << 3, tx0 = (tile & 15) << 3;

    for (int i = tid; i < 1152; i += 256) wds[i] = dw[i];
    for (int i = tid; i < 576; i += 256) wcs[i] = cwgt[i];
    if (tid == 0) { wds[1152] = db[0]; wds[1153] = db[1]; wcs[576] = cb[0]; }

    // GN stats fold (256 convgn-blocks per batch)
    {
        int g = tid >> 5, i = tid & 31;
        float s = 0.f, s2 = 0.f;
#pragma unroll
        for (int k = 0; k < 8; k++) {
            int pb = b * 256 + i + k * 32;
            s  += pbuf[(pb * 8 + g) * 2];
            s2 += pbuf[(pb * 8 + g) * 2 + 1];
        }
#pragma unroll
        for (int m = 1; m < 32; m <<= 1) { s += __shfl_xor(s, m); s2 += __shfl_xor(s2, m); }
        if (i == 0) {
            const float inv = 1.f / 131072.f;
            float mean = s * inv;
            float var = fmaxf(s2 * inv - mean * mean, 0.f);
            sm[g * 2] = mean;
            sm[g * 2 + 1] = rsqrtf(var + 1e-5f);
        }
    }
    __syncthreads();

    // load halo + GN + GELU into LDS: 100 slots x 8 ch-octets = 800 items
#pragma unroll
    for (int pass = 0; pass < 4; pass++) {
        int idx = pass * 256 + tid;
        if (idx < 800) {
            int slot = idx >> 3, c8 = idx & 7;
            int py = slot / 10, px = slot - py * 10;
            int gy = ty0 + py - 1, gx = tx0 + px - 1;
            u16x8 o = {0, 0, 0, 0, 0, 0, 0, 0};
            if ((unsigned)gy < 128u && (unsigned)gx < 128u) {
                int gpix = (b << 14) + (gy << 7) + gx;
                u16x8 v = *(const u16x8*)(hpre + (size_t)gpix * HID + c8 * 8);
                float mean = sm[c8 * 2], rstd = sm[c8 * 2 + 1];
#pragma unroll
                for (int i = 0; i < 8; i++) {
                    int c = c8 * 8 + i;
                    float xn = (bf2f(v[i]) - mean) * rstd * gamma[c] + beta[c];
                    float ge = 0.5f * xn * (1.f + erff(xn * 0.70710678118654752f));
                    o[i] = f2bf(ge);
                }
            }
            *(u16x8*)(&hnT[slot * 68 + c8 * 8]) = o;
        }
    }
    __syncthreads();

    // heads: px p = tid>>2 (8x8 interior), part = tid&3 (2 ch-octets each)
    int p = tid >> 2, part = tid & 3;
    int py = (p >> 3) + 1, px = (p & 7) + 1;
    float d0 = 0.f, d1 = 0.f, c0 = 0.f;
#pragma unroll
    for (int ky = 0; ky < 3; ky++)
#pragma unroll
        for (int kx = 0; kx < 3; kx++) {
            const unsigned short* hp = &hnT[((py + ky - 1) * 10 + (px + kx - 1)) * 68];
            int widx = ky * 3 + kx;
#pragma unroll
            for (int cc = 0; cc < 2; cc++) {
                int c8 = part * 2 + cc;
                u16x8 v = *(const u16x8*)(hp + c8 * 8);
#pragma unroll
                for (int i = 0; i < 8; i++) {
                    float f = bf2f(v[i]);
                    int c = c8 * 8 + i;
                    d0 += f * wds[c * 9 + widx];
                    d1 += f * wds[576 + c * 9 + widx];
                    c0 += f * wcs[c * 9 + widx];
                }
            }
        }
#pragma unroll
    for (int m = 1; m < 4; m <<= 1) {
        d0 += __shfl_xor(d0, m);
        d1 += __shfl_xor(d1, m);
        c0 += __shfl_xor(c0, m);
    }
    if (part == 0) {
        int pix = (b << 14) + ((ty0 + py - 1) << 7) + (tx0 + px - 1);
        d0 = tanhf(d0 + wds[1152]);
        d1 = tanhf(d1 + wds[1153]);
        c0 += wcs[576];

        float gx = clean15(cw[(size_t)pix * 2 + 0]);
        float gy = clean15(cw[(size_t)pix * 2 + 1]);
        float fwx = fminf(fmaxf(gx + d0 * 0.0625f, -1.5f), 1.5f);
        float fwy = fminf(fmaxf(gy + d1 * 0.0625f, -1.5f), 1.5f);

        float conf = clean01(confp[pix]);
        float pp = fminf(fmaxf(conf, 1e-4f), 1.f - 1e-4f);
        float bl = logf(pp) - log1pf(-pp);
        float rl = bl + 0.5f * c0;
        float rc = fminf(fmaxf(1.f / (1.f + expf(-rl)), 0.f), 1.f);

        out[(size_t)pix * 2 + 0] = fwx;
        out[(size_t)pix * 2 + 1] = fwy;
        out[(size_t)NPIX * 2 + pix] = rc;
        out[(size_t)NPIX * 2 + NPIX + pix] = rl;
    }
}

// ---------------- launcher ----------------
extern "C" void kernel_launch(void* const* d_in, const int* in_sizes, int n_in,
                              void* d_out, int out_size, void* d_ws, size_t ws_size,
                              hipStream_t stream)
{
    const float* feat_A = (const float*)d_in[0];
    const float* feat_B = (const float*)d_in[1];
    const float* cw     = (const float*)d_in[2];
    const float* conf   = (const float*)d_in[3];
    const float* w1     = (const float*)d_in[4];
    const float* g1     = (const float*)d_in[5];
    const float* b1     = (const float*)d_in[6];
    const float* w2     = (const float*)d_in[7];
    const float* g2     = (const float*)d_in[8];
    const float* b2     = (const float*)d_in[9];
    const float* w3     = (const float*)d_in[10];
    const float* g3     = (const float*)d_in[11];
    const float* b3     = (const float*)d_in[12];
    const float* dw     = (const float*)d_in[13];
    const float* db     = (const float*)d_in[14];
    const float* cwgt   = (const float*)d_in[15];
    const float* cb     = (const float*)d_in[16];
    float* out = (float*)d_out;

    char* w = (char*)d_ws;
    size_t o = 0;
    unsigned short* faT  = (unsigned short*)(w + o); o += (size_t)NPIX * C_ * 2;     // 16 MB
    unsigned short* fbT  = (unsigned short*)(w + o); o += (size_t)NPIX * C_ * 2;     // 16 MB
    unsigned short* wbb  = (unsigned short*)(w + o); o += (size_t)NPIX * C_ * 2;     // 16 MB
    unsigned short* tail = (unsigned short*)(w + o); o += (size_t)NPIX * 32 * 2;     // 2 MB
    unsigned short* hA   = (unsigned short*)(w + o); o += (size_t)NPIX * HID * 2;    // 4 MB
    unsigned short* hB   = (unsigned short*)(w + o); o += (size_t)NPIX * HID * 2;    // 4 MB
    unsigned short* p1   = (unsigned short*)(w + o); o += (size_t)K1STEPS * 4 * 64 * 8 * 2;
    unsigned short* p2   = (unsigned short*)(w + o); o += (size_t)K3STEPS * 4 * 64 * 8 * 2;
    unsigned short* p3   = (unsigned short*)(w + o); o += (size_t)K3STEPS * 4 * 64 * 8 * 2;
    float* pbuf1 = (float*)(w + o); o += 512 * 8 * 2 * 4;
    float* pbuf2 = (float*)(w + o); o += 512 * 8 * 2 * 4;
    float* pbuf3 = (float*)(w + o); o += 512 * 8 * 2 * 4;

    k_transpose<<<dim3(PIX_PER / 32, C_ / 32, 5), 256, 0, stream>>>(feat_A, feat_B, faT, fbT,
                                                                    w1, w2, w3, p1, p2, p3);
    k_sample<<<NPIX / 4, 256, 0, stream>>>(cw, conf, faT, fbT, wbb, tail);

    k_gemm1<<<(NPIX / 16) / 4, 256, 0, stream>>>(faT, wbb, tail, p1, hA, pbuf1);
    k_convgn<<<512, 256, 0, stream>>>(hA, g1, b1, pbuf1, p2, hB, pbuf2);
    k_convgn<<<512, 256, 0, stream>>>(hB, g2, b2, pbuf2, p3, hA, pbuf3);
    k_gnfinal<<<512, 256, 0, stream>>>(hA, g3, b3, pbuf3, cw, conf,
                                       dw, db, cwgt, cb, out);
}

// Round 16
// 122.425 us; speedup vs baseline: 1.5754x; 1.0305x over previous
//
#include <hip/hip_runtime.h>
#include <hip/hip_bf16.h>
#include <math.h>

#define B_ 2
#define H_ 128
#define W_ 128
#define C_ 256
#define HID 64
#define PIX_PER (H_*W_)          // 16384
#define NPIX (B_*PIX_PER)        // 32768
#define K1STEPS 25               // 800 / 32 (fa 0-7, wb 8-15, diff 16-23, tail 24)
#define K3STEPS 18               // 576 / 32
#define SROW 264                 // LDS tap-row stride in u16 (528B = 16B-aligned; do NOT shrink)
#define CTS 16                   // CT row stride in f32 (16B-aligned stores)

using f32x4 = __attribute__((ext_vector_type(4))) float;
using s16x8 = __attribute__((ext_vector_type(8))) short;
using u16x2 = __attribute__((ext_vector_type(2))) unsigned short;
using u16x4 = __attribute__((ext_vector_type(4))) unsigned short;
using u16x8 = __attribute__((ext_vector_type(8))) unsigned short;

__device__ __forceinline__ float bf2f(unsigned short u) {
    return __uint_as_float(((unsigned)u) << 16);
}
__device__ __forceinline__ unsigned short f2bf(float f) {
    unsigned u = __float_as_uint(f);
    u += 0x7FFFu + ((u >> 16) & 1u);
    return (unsigned short)(u >> 16);
}
__device__ __forceinline__ float clean15(float v) {
    if (v != v) v = 0.f;
    return fminf(fmaxf(v, -1.5f), 1.5f);
}
__device__ __forceinline__ float clean01(float v) {
    if (v != v) v = 0.f;
    return fminf(fmaxf(v, 0.f), 1.f);
}

// ---------------- transpose NCHW -> NHWC bf16 (+ weight pack on z==4) ----------------
// 64-wide tiles, float4 loads (16B/lane). Write phase race-audited: each
// (hw, ch-quad) task exactly once, all writes inside this block's 32 channels.
__global__ __launch_bounds__(256) void k_transpose(const float* __restrict__ A,
                                                   const float* __restrict__ Bm,
                                                   unsigned short* __restrict__ faT,
                                                   unsigned short* __restrict__ fbT,
                                                   const float* __restrict__ w1,
                                                   const float* __restrict__ w2,
                                                   const float* __restrict__ w3,
                                                   unsigned short* __restrict__ p1,
                                                   unsigned short* __restrict__ p2,
                                                   unsigned short* __restrict__ p3)
{
    if (blockIdx.z == 4) {              // weight-pack slice
        if (blockIdx.y != 0 || blockIdx.x >= 61) return;
        int t = blockIdx.x * 256 + threadIdx.x;
        if (t < 6400) {                                   // enc1: 25 ksteps
            int lane = t & 63, nt = (t >> 6) & 3, ks = t >> 8;
            int n = nt * 16 + (lane & 15);
            int kb = ks * 32 + 8 * (lane >> 4);
#pragma unroll
            for (int j = 0; j < 8; j++) {
                int k = kb + j;
                p1[(size_t)t * 8 + j] = (k < 780) ? f2bf(w1[(size_t)n * 780 + k]) : (unsigned short)0;
            }
        } else if (t < 6400 + 2 * 4608) {                 // enc2/enc3: 18 ksteps each
            int which = (t - 6400) / 4608;
            int idx = (t - 6400) % 4608;
            const float* w = which ? w3 : w2;
            unsigned short* p = which ? p3 : p2;
            int lane = idx & 63, nt = (idx >> 6) & 3, ks = idx >> 8;
            int n = nt * 16 + (lane & 15);
            int tap = ks >> 1;
            int ky = tap / 3, kx = tap % 3;
#pragma unroll
            for (int j = 0; j < 8; j++) {
                int c = (ks & 1) * 32 + 8 * (lane >> 4) + j;
                p[(size_t)idx * 8 + j] = f2bf(w[(((size_t)n * 64 + c) * 3 + ky) * 3 + kx]);
            }
        }
        return;
    }
    __shared__ float tile[32][68];       // 272B rows: f32x4 stores stay aligned
    int hw0 = blockIdx.x * 64;
    int c0  = blockIdx.y * 32;
    int z   = blockIdx.z;                // b*2 + which
    int b   = z >> 1;
    const float* src = (z & 1) ? Bm : A;
    unsigned short* dst = (z & 1) ? fbT : faT;
    int tx = threadIdx.x & 15, ty = threadIdx.x >> 4;   // 16 x 16
    const float* s = src + ((size_t)b * C_ + c0) * (size_t)PIX_PER + hw0;
#pragma unroll
    for (int i = 0; i < 32; i += 16) {
        int c = ty + i;
        f32x4 v = *(const f32x4*)(s + (size_t)c * PIX_PER + tx * 4);
#pragma unroll
        for (int j = 0; j < 4; j++)
            if (!isfinite(v[j])) v[j] = 0.f;
        *(f32x4*)&tile[c][tx * 4] = v;
    }
    __syncthreads();
    unsigned short* d = dst + ((size_t)b * PIX_PER + hw0) * C_ + c0;
#pragma unroll
    for (int it = 0; it < 2; it++) {
        int idx = it * 256 + threadIdx.x;
        int pr = idx & 7;                 // channel quad (4pr+3 <= 31: in-block)
        int hw = idx >> 3;                // 0..63
        u16x4 o;
#pragma unroll
        for (int j = 0; j < 4; j++) o[j] = f2bf(tile[4 * pr + j][hw]);
        *(u16x4*)(d + (size_t)hw * C_ + 4 * pr) = o;
    }
}

// ---------------- sampling via per-pixel Gram MFMA, LDS-staged taps (r7, verified) ----------------
// CT stride 16 (was 20): LDS 41088 -> 40000 B => 4 blocks/CU (16 waves, was 12).
__global__ __launch_bounds__(256) void k_sample(const float* __restrict__ cw,
                                                const float* __restrict__ confp,
                                                const unsigned short* __restrict__ faT,
                                                const unsigned short* __restrict__ fbT,
                                                unsigned short* __restrict__ wbbuf,
                                                unsigned short* __restrict__ tail)
{
    __shared__ unsigned short S[4][17 * SROW];   // 35904 B: 16 taps + fa per wave
    __shared__ float CT[4][16 * CTS];            // 4096 B: Gram C^T per wave
    int lane = threadIdx.x & 63;
    int wv = threadIdx.x >> 6;
    int wid = blockIdx.x * 4 + wv;
    int b = wid >> 14, y = (wid >> 7) & 127, x = wid & 127;

    float gx = clean15(cw[(size_t)wid * 2 + 0]);
    float gy = clean15(cw[(size_t)wid * 2 + 1]);
    float conf = clean01(confp[wid]);

    float pxu = (gx + 1.f) * 64.f - 0.5f;
    float pyu = (gy + 1.f) * 64.f - 0.5f;
    float x0f = floorf(pxu), y0f = floorf(pyu);
    float wx = pxu - x0f, wy = pyu - y0f;
    int x0 = (int)x0f, y0 = (int)y0f;
    int co[4], ro[4];
#pragma unroll
    for (int k = 0; k < 4; k++) {
        co[k] = min(max(x0 - 1 + k, 0), 127) << 8;
        ro[k] = min(max(y0 - 1 + k, 0), 127) << 15;
    }
    const unsigned short* fbP = fbT + ((size_t)b << 22);

    // stage: issue all 9 coalesced loads first, then LDS writes
    int h = lane >> 5, lo = lane & 31;
    u16x8 stg[8];
#pragma unroll
    for (int i = 0; i < 8; i++) {
        int rr = ro[i >> 1];
        int cc = h ? co[((i & 1) << 1) + 1] : co[(i & 1) << 1];
        stg[i] = *(const u16x8*)(fbP + rr + cc + lo * 8);
    }
    u16x8 stfa;
    if (h == 0) stfa = *(const u16x8*)(faT + (size_t)wid * C_ + lo * 8);

    unsigned short* Sw = &S[wv][0];
#pragma unroll
    for (int i = 0; i < 8; i++)
        *(u16x8*)(Sw + (2 * i + h) * SROW + lo * 8) = stg[i];
    if (h == 0) *(u16x8*)(Sw + 16 * SROW + lo * 8) = stfa;

    // Gram via 8 MFMAs, fragments from LDS
    int q = lane & 15;
    int tA = (q == 0) ? 16 : q - 1;
    int koff = (lane >> 4) * 8;
    const unsigned short* pA = Sw + tA * SROW + koff;
    const unsigned short* pB = Sw + q * SROW + koff;
    f32x4 acc = {0.f, 0.f, 0.f, 0.f};
#pragma unroll
    for (int ks = 0; ks < 8; ks++) {
        s16x8 av = *(const s16x8*)(pA + ks * 32);
        s16x8 bv = *(const s16x8*)(pB + ks * 32);
        acc = __builtin_amdgcn_mfma_f32_16x16x32_bf16(av, bv, acc, 0, 0, 0);
    }
    *(f32x4*)&CT[wv][q * CTS + (lane >> 4) * 4] = acc;

    // wb (center bilerp) + fa^2 / t15^2 partials, all from LDS
    float w00 = (1.f - wx) * (1.f - wy), w01 = wx * (1.f - wy);
    float w10 = (1.f - wx) * wy,         w11 = wx * wy;
    u16x4 v5  = *(const u16x4*)(Sw + 5 * SROW + lane * 4);
    u16x4 v6  = *(const u16x4*)(Sw + 6 * SROW + lane * 4);
    u16x4 v9  = *(const u16x4*)(Sw + 9 * SROW + lane * 4);
    u16x4 v10 = *(const u16x4*)(Sw + 10 * SROW + lane * 4);
    u16x4 v15 = *(const u16x4*)(Sw + 15 * SROW + lane * 4);
    u16x4 vfa = *(const u16x4*)(Sw + 16 * SROW + lane * 4);
    float fa2p = 0.f, t152p = 0.f;
    u16x4 wbo;
#pragma unroll
    for (int i = 0; i < 4; i++) {
        float s = w00 * bf2f(v5[i]) + w01 * bf2f(v6[i])
                + w10 * bf2f(v9[i]) + w11 * bf2f(v10[i]);
        wbo[i] = f2bf(s);
        float fv = bf2f(vfa[i]), tv = bf2f(v15[i]);
        fa2p  += fv * fv;
        t152p += tv * tv;
    }
    *(u16x4*)(wbbuf + (size_t)wid * C_ + lane * 4) = wbo;
#pragma unroll
    for (int m = 1; m < 64; m <<= 1) {
        fa2p  += __shfl_xor(fa2p, m);
        t152p += __shfl_xor(t152p, m);
    }

    // epilogue: lanes 0..31 assemble the 32-entry tail row
    if (lane < 32) {
        float outv = 0.f;
        if (lane == 0)      outv = gx - (((float)x + 0.5f) * 0.015625f - 1.f);
        else if (lane == 1) outv = gy - (((float)y + 0.5f) * 0.015625f - 1.f);
        else if (lane == 2) outv = conf;
        else if (lane < 12) {
            int j = lane - 3;
            int jd = j / 3, jm = j - jd * 3;
            int m00 = jd * 4 + jm;
            const float* Cw = &CT[wv][0];
            float D00 = Cw[m00 * CTS], D01 = Cw[(m00 + 1) * CTS];
            float D10 = Cw[(m00 + 4) * CTS], D11 = Cw[(m00 + 5) * CTS];
            float dot = w00 * D00 + w01 * D01 + w10 * D10 + w11 * D11;
#define GR(a, b) Cw[(b) * CTS + (a) + 1]
            float g11 = (j == 8) ? t152p : GR(m00 + 5, m00 + 5);
            float s2 = w00 * w00 * GR(m00, m00) + w01 * w01 * GR(m00 + 1, m00 + 1)
                     + w10 * w10 * GR(m00 + 4, m00 + 4) + w11 * w11 * g11
                     + 2.f * (w00 * w01 * GR(m00, m00 + 1) + w00 * w10 * GR(m00, m00 + 4)
                            + w00 * w11 * GR(m00, m00 + 5) + w01 * w10 * GR(m00 + 1, m00 + 4)
                            + w01 * w11 * GR(m00 + 1, m00 + 5) + w10 * w11 * GR(m00 + 4, m00 + 5));
#undef GR
            outv = dot * rsqrtf(fmaxf(fa2p, 1e-24f)) * rsqrtf(fmaxf(s2, 1e-24f));
        }
        tail[(size_t)wid * 32 + lane] = f2bf(outv);
    }
}

// ---- GN partial-stats epilogue shared by gemm1/convgn (per-block partials) ----
__device__ __forceinline__ void gn_epilogue(const f32x4 acc[4], float* lds,
                                            float* __restrict__ pbuf, int bid,
                                            int la, int lb, int wv)
{
    int d = la >> 3;
    int slot = wv * 32 + lb * 8 + (la & 7);
#pragma unroll
    for (int nt = 0; nt < 4; nt++) {
        float s  = acc[nt][0] + acc[nt][1] + acc[nt][2] + acc[nt][3];
        float s2 = acc[nt][0] * acc[nt][0] + acc[nt][1] * acc[nt][1]
                 + acc[nt][2] * acc[nt][2] + acc[nt][3] * acc[nt][3];
        int g = nt * 2 + d;
        lds[(g * 128 + slot) * 2 + 0] = s;
        lds[(g * 128 + slot) * 2 + 1] = s2;
    }
    __syncthreads();
    int tid = threadIdx.x;
    int g = tid >> 5, i = tid & 31;
    float s  = lds[(g * 128 + i) * 2]     + lds[(g * 128 + i + 32) * 2]
             + lds[(g * 128 + i + 64) * 2] + lds[(g * 128 + i + 96) * 2];
    float s2 = lds[(g * 128 + i) * 2 + 1]     + lds[(g * 128 + i + 32) * 2 + 1]
             + lds[(g * 128 + i + 64) * 2 + 1] + lds[(g * 128 + i + 96) * 2 + 1];
#pragma unroll
    for (int m = 1; m < 32; m <<= 1) { s += __shfl_xor(s, m); s2 += __shfl_xor(s2, m); }
    if (i == 0) {
        pbuf[(bid * 8 + g) * 2]     = s;
        pbuf[(bid * 8 + g) * 2 + 1] = s2;
    }
}

// ---------------- conv1x1 as MFMA GEMM, A assembled on the fly ----------------
__global__ __launch_bounds__(256) void k_gemm1(const unsigned short* __restrict__ faT,
                                               const unsigned short* __restrict__ wbbuf,
                                               const unsigned short* __restrict__ tail,
                                               const unsigned short* __restrict__ pack,
                                               unsigned short* __restrict__ hpre,
                                               float* __restrict__ pbuf)
{
    __shared__ float lds[8 * 128 * 2];
    int wave = (blockIdx.x * 256 + threadIdx.x) >> 6;
    int lane = threadIdx.x & 63;
    int la = lane & 15, lb = lane >> 4;
    int row = wave * 16 + la;
    const unsigned short* fa_row = faT   + (size_t)row * C_ + lb * 8;
    const unsigned short* wb_row = wbbuf + (size_t)row * C_ + lb * 8;
    f32x4 acc[4] = {{0,0,0,0},{0,0,0,0},{0,0,0,0},{0,0,0,0}};

#pragma unroll
    for (int ks = 0; ks < 8; ks++) {
        s16x8 a = *(const s16x8*)(fa_row + ks * 32);
#pragma unroll
        for (int nt = 0; nt < 4; nt++)
            acc[nt] = __builtin_amdgcn_mfma_f32_16x16x32_bf16(a,
                *(const s16x8*)(pack + ((size_t)(ks * 4 + nt) * 64 + lane) * 8), acc[nt], 0, 0, 0);
    }
#pragma unroll
    for (int ks = 0; ks < 8; ks++) {
        s16x8 a = *(const s16x8*)(wb_row + ks * 32);
#pragma unroll
        for (int nt = 0; nt < 4; nt++)
            acc[nt] = __builtin_amdgcn_mfma_f32_16x16x32_bf16(a,
                *(const s16x8*)(pack + ((size_t)((ks + 8) * 4 + nt) * 64 + lane) * 8), acc[nt], 0, 0, 0);
    }
#pragma unroll
    for (int ks = 0; ks < 8; ks++) {
        u16x8 av = *(const u16x8*)(fa_row + ks * 32);
        u16x8 bv = *(const u16x8*)(wb_row + ks * 32);
        s16x8 a;
#pragma unroll
        for (int j = 0; j < 8; j++)
            a[j] = (short)f2bf(fabsf(bf2f(av[j]) - bf2f(bv[j])));
#pragma unroll
        for (int nt = 0; nt < 4; nt++)
            acc[nt] = __builtin_amdgcn_mfma_f32_16x16x32_bf16(a,
                *(const s16x8*)(pack + ((size_t)((ks + 16) * 4 + nt) * 64 + lane) * 8), acc[nt], 0, 0, 0);
    }
    {
        s16x8 a = *(const s16x8*)(tail + (size_t)row * 32 + lb * 8);
#pragma unroll
        for (int nt = 0; nt < 4; nt++)
            acc[nt] = __builtin_amdgcn_mfma_f32_16x16x32_bf16(a,
                *(const s16x8*)(pack + ((size_t)(24 * 4 + nt) * 64 + lane) * 8), acc[nt], 0, 0, 0);
    }

    int orow = wave * 16 + lb * 4;
#pragma unroll
    for (int nt = 0; nt < 4; nt++)
#pragma unroll
        for (int r = 0; r < 4; r++)
            hpre[(size_t)(orow + r) * HID + nt * 16 + la] = f2bf(acc[nt][r]);

    gn_epilogue(acc, lds, pbuf, blockIdx.x, la, lb, (threadIdx.x >> 6));
}

// ------- fused GN + GELU + conv3x3 (r12-verified): 8x8 tile per block -------
__global__ __launch_bounds__(256) void k_convgn(const unsigned short* __restrict__ hin,
                                                const float* __restrict__ gamma,
                                                const float* __restrict__ beta,
                                                const float* __restrict__ pbin,
                                                const unsigned short* __restrict__ pack,
                                                unsigned short* __restrict__ hout,
                                                float* __restrict__ pbout)
{
    __shared__ unsigned short T[8 * 100 * 8];   // [c8][py*10+px][8ch] = 12800 B
    __shared__ float eplds[8 * 128 * 2];        // 8 KB
    __shared__ float sm[16];
    int tid = threadIdx.x;
    int bid = blockIdx.x;                        // 512 = 2 batches x 16x16 tiles
    int b = bid >> 8;
    int tile = bid & 255;
    int ty0 = (tile >> 4) << 3, tx0 = (tile & 15) << 3;

    // fold prev-layer GN stats (256 partial-blocks per batch)
    {
        int g = tid >> 5, i = tid & 31;
        float s = 0.f, s2 = 0.f;
#pragma unroll
        for (int k = 0; k < 8; k++) {
            int pb = b * 256 + i + k * 32;
            s  += pbin[(pb * 8 + g) * 2];
            s2 += pbin[(pb * 8 + g) * 2 + 1];
        }
#pragma unroll
        for (int m = 1; m < 32; m <<= 1) { s += __shfl_xor(s, m); s2 += __shfl_xor(s2, m); }
        if (i == 0) {
            const float inv = 1.f / 131072.f;
            float mean = s * inv;
            float var = fmaxf(s2 * inv - mean * mean, 0.f);
            sm[g * 2] = mean;
            sm[g * 2 + 1] = rsqrtf(var + 1e-5f);
        }
    }
    __syncthreads();

    // stage 10x10 halo with GN+GELU: 100 slots x 8 ch-octets = 800 tasks
#pragma unroll
    for (int pass = 0; pass < 4; pass++) {
        int idx = pass * 256 + tid;
        if (idx < 800) {
            int c8 = idx & 7, slot = idx >> 3;
            int py = slot / 10, px = slot - py * 10;
            int gy = ty0 + py - 1, gx = tx0 + px - 1;
            u16x8 o = {0, 0, 0, 0, 0, 0, 0, 0};
            if ((unsigned)gy < 128u && (unsigned)gx < 128u) {
                int gpix = (b << 14) + (gy << 7) + gx;
                u16x8 v = *(const u16x8*)(hin + (size_t)gpix * HID + c8 * 8);
                float mean = sm[c8 * 2], rstd = sm[c8 * 2 + 1];
#pragma unroll
                for (int i = 0; i < 8; i++) {
                    int c = c8 * 8 + i;
                    float xn = (bf2f(v[i]) - mean) * rstd * gamma[c] + beta[c];
                    o[i] = f2bf(0.5f * xn * (1.f + erff(xn * 0.70710678118654752f)));
                }
            }
            *(u16x8*)(&T[(c8 * 100 + slot) * 8]) = o;
        }
    }
    __syncthreads();

    // conv3x3: wave wv -> output rows {2wv, 2wv+1} of the 8x8 tile
    int lane = tid & 63, wv = tid >> 6;
    int la = lane & 15, lb = lane >> 4;
    int ay = la >> 3, ax = la & 7;              // A-row la -> (row-pair offset, x)
    f32x4 acc[4] = {{0,0,0,0},{0,0,0,0},{0,0,0,0},{0,0,0,0}};
#pragma unroll
    for (int ks = 0; ks < K3STEPS; ks++) {
        int tap = ks >> 1;
        int dy = tap / 3, dx = tap - dy * 3;
        int c8 = (ks & 1) * 4 + lb;
        int py = wv * 2 + ay + dy;
        int px = ax + dx;
        s16x8 a = *(const s16x8*)(&T[(c8 * 100 + py * 10 + px) * 8]);
#pragma unroll
        for (int nt = 0; nt < 4; nt++)
            acc[nt] = __builtin_amdgcn_mfma_f32_16x16x32_bf16(a,
                *(const s16x8*)(pack + ((size_t)(ks * 4 + nt) * 64 + lane) * 8), acc[nt], 0, 0, 0);
    }

    // write pre-GN output: C row = px_off = lb*4+r -> (y = +po>>3, x = po&7)
#pragma unroll
    for (int nt = 0; nt < 4; nt++)
#pragma unroll
        for (int r = 0; r < 4; r++) {
            int po = lb * 4 + r;
            int yy = ty0 + wv * 2 + (po >> 3);
            int xx = tx0 + (po & 7);
            hout[((size_t)((b << 14) + (yy << 7) + xx)) * HID + nt * 16 + la] = f2bf(acc[nt][r]);
        }

    gn_epilogue(acc, eplds, pbout, bid, la, lb, wv);
}

// ------- fused GN3 + GELU + delta/conf heads + epilogue (verified r11) -------
__global__ __launch_bounds__(256) void k_gnfinal(const unsigned short* __restrict__ hpre,
                                                 const float* __restrict__ gamma,
                                                 const float* __restrict__ beta,
                                                 const float* __restrict__ pbuf,
                                                 const float* __restrict__ cw,
                                                 const float* __restrict__ confp,
                                                 const float* __restrict__ dw,
                                                 const float* __restrict__ db,
                                                 const float* __restrict__ cwgt,
                                                 const float* __restrict__ cb,
                                                 float* __restrict__ out)
{
    __shared__ unsigned short hnT[100 * 68];   // 10x10 px, 64 ch + 4 pad (13.6 KB)
    __shared__ float wds[1154];
    __shared__ float wcs[577];
    __shared__ float sm[16];
    int tid = threadIdx.x;
    int bid = blockIdx.x;                       // 512 = 2 batches x 16x16 tiles
    int b = bid >> 8;
    int tile = bid & 255;
    int ty0 = (tile >> 4) << 3, tx0 = (tile & 15) << 3;

    for (int i = tid; i < 1152; i += 256) wds[i] = dw[i];
    for (int i = tid; i < 576; i += 256) wcs[i] = cwgt[i];
    if (tid == 0) { wds[1152] = db[0]; wds[1153] = db[1]; wcs[576] = cb[0]; }

    // GN stats fold (256 convgn-blocks per batch)
    {
        int g = tid >> 5, i = tid & 31;
        float s = 0.f, s2 = 0.f;
#pragma unroll
        for (int k = 0; k < 8; k++) {
            int pb = b * 256 + i + k * 32;
            s  += pbuf[(pb * 8 + g) * 2];
            s2 += pbuf[(pb * 8 + g) * 2 + 1];
        }
#pragma unroll
        for (int m = 1; m < 32; m <<= 1) { s += __shfl_xor(s, m); s2 += __shfl_xor(s2, m); }
        if (i == 0) {
            const float inv = 1.f / 131072.f;
            float mean = s * inv;
            float var = fmaxf(s2 * inv - mean * mean, 0.f);
            sm[g * 2] = mean;
            sm[g * 2 + 1] = rsqrtf(var + 1e-5f);
        }
    }
    __syncthreads();

    // load halo + GN + GELU into LDS: 100 slots x 8 ch-octets = 800 items
#pragma unroll
    for (int pass = 0; pass < 4; pass++) {
        int idx = pass * 256 + tid;
        if (idx < 800) {
            int slot = idx >> 3, c8 = idx & 7;
            int py = slot / 10, px = slot - py * 10;
            int gy = ty0 + py - 1, gx = tx0 + px - 1;
            u16x8 o = {0, 0, 0, 0, 0, 0, 0, 0};
            if ((unsigned)gy < 128u && (unsigned)gx < 128u) {
                int gpix = (b << 14) + (gy << 7) + gx;
                u16x8 v = *(const u16x8*)(hpre + (size_t)gpix * HID + c8 * 8);
                float mean = sm[c8 * 2], rstd = sm[c8 * 2 + 1];
#pragma unroll
                for (int i = 0; i < 8; i++) {
                    int c = c8 * 8 + i;
                    float xn = (bf2f(v[i]) - mean) * rstd * gamma[c] + beta[c];
                    float ge = 0.5f * xn * (1.f + erff(xn * 0.70710678118654752f));
                    o[i] = f2bf(ge);
                }
            }
            *(u16x8*)(&hnT[slot * 68 + c8 * 8]) = o;
        }
    }
    __syncthreads();

    // heads: px p = tid>>2 (8x8 interior), part = tid&3 (2 ch-octets each)
    int p = tid >> 2, part = tid & 3;
    int py = (p >> 3) + 1, px = (p & 7) + 1;
    float d0 = 0.f, d1 = 0.f, c0 = 0.f;
#pragma unroll
    for (int ky = 0; ky < 3; ky++)
#pragma unroll
        for (int kx = 0; kx < 3; kx++) {
            const unsigned short* hp = &hnT[((py + ky - 1) * 10 + (px + kx - 1)) * 68];
            int widx = ky * 3 + kx;
#pragma unroll
            for (int cc = 0; cc < 2; cc++) {
                int c8 = part * 2 + cc;
                u16x8 v = *(const u16x8*)(hp + c8 * 8);
#pragma unroll
                for (int i = 0; i < 8; i++) {
                    float f = bf2f(v[i]);
                    int c = c8 * 8 + i;
                    d0 += f * wds[c * 9 + widx];
                    d1 += f * wds[576 + c * 9 + widx];
                    c0 += f * wcs[c * 9 + widx];
                }
            }
        }
#pragma unroll
    for (int m = 1; m < 4; m <<= 1) {
        d0 += __shfl_xor(d0, m);
        d1 += __shfl_xor(d1, m);
        c0 += __shfl_xor(c0, m);
    }
    if (part == 0) {
        int pix = (b << 14) + ((ty0 + py - 1) << 7) + (tx0 + px - 1);
        d0 = tanhf(d0 + wds[1152]);
        d1 = tanhf(d1 + wds[1153]);
        c0 += wcs[576];

        float gx = clean15(cw[(size_t)pix * 2 + 0]);
        float gy = clean15(cw[(size_t)pix * 2 + 1]);
        float fwx = fminf(fmaxf(gx + d0 * 0.0625f, -1.5f), 1.5f);
        float fwy = fminf(fmaxf(gy + d1 * 0.0625f, -1.5f), 1.5f);

        float conf = clean01(confp[pix]);
        float pp = fminf(fmaxf(conf, 1e-4f), 1.f - 1e-4f);
        float bl = logf(pp) - log1pf(-pp);
        float rl = bl + 0.5f * c0;
        float rc = fminf(fmaxf(1.f / (1.f + expf(-rl)), 0.f), 1.f);

        out[(size_t)pix * 2 + 0] = fwx;
        out[(size_t)pix * 2 + 1] = fwy;
        out[(size_t)NPIX * 2 + pix] = rc;
        out[(size_t)NPIX * 2 + NPIX + pix] = rl;
    }
}

// ---------------- launcher ----------------
extern "C" void kernel_launch(void* const* d_in, const int* in_sizes, int n_in,
                              void* d_out, int out_size, void* d_ws, size_t ws_size,
                              hipStream_t stream)
{
    const float* feat_A = (const float*)d_in[0];
    const float* feat_B = (const float*)d_in[1];
    const float* cw     = (const float*)d_in[2];
    const float* conf   = (const float*)d_in[3];
    const float* w1     = (const float*)d_in[4];
    const float* g1     = (const float*)d_in[5];
    const float* b1     = (const float*)d_in[6];
    const float* w2     = (const float*)d_in[7];
    const float* g2     = (const float*)d_in[8];
    const float* b2     = (const float*)d_in[9];
    const float* w3     = (const float*)d_in[10];
    const float* g3     = (const float*)d_in[11];
    const float* b3     = (const float*)d_in[12];
    const float* dw     = (const float*)d_in[13];
    const float* db     = (const float*)d_in[14];
    const float* cwgt   = (const float*)d_in[15];
    const float* cb     = (const float*)d_in[16];
    float* out = (float*)d_out;

    char* w = (char*)d_ws;
    size_t o = 0;
    unsigned short* faT  = (unsigned short*)(w + o); o += (size_t)NPIX * C_ * 2;     // 16 MB
    unsigned short* fbT  = (unsigned short*)(w + o); o += (size_t)NPIX * C_ * 2;     // 16 MB
    unsigned short* wbb  = (unsigned short*)(w + o); o += (size_t)NPIX * C_ * 2;     // 16 MB
    unsigned short* tail = (unsigned short*)(w + o); o += (size_t)NPIX * 32 * 2;     // 2 MB
    unsigned short* hA   = (unsigned short*)(w + o); o += (size_t)NPIX * HID * 2;    // 4 MB
    unsigned short* hB   = (unsigned short*)(w + o); o += (size_t)NPIX * HID * 2;    // 4 MB
    unsigned short* p1   = (unsigned short*)(w + o); o += (size_t)K1STEPS * 4 * 64 * 8 * 2;
    unsigned short* p2   = (unsigned short*)(w + o); o += (size_t)K3STEPS * 4 * 64 * 8 * 2;
    unsigned short* p3   = (unsigned short*)(w + o); o += (size_t)K3STEPS * 4 * 64 * 8 * 2;
    float* pbuf1 = (float*)(w + o); o += 512 * 8 * 2 * 4;
    float* pbuf2 = (float*)(w + o); o += 512 * 8 * 2 * 4;
    float* pbuf3 = (float*)(w + o); o += 512 * 8 * 2 * 4;

    k_transpose<<<dim3(PIX_PER / 64, C_ / 32, 5), 256, 0, stream>>>(feat_A, feat_B, faT, fbT,
                                                                    w1, w2, w3, p1, p2, p3);
    k_sample<<<NPIX / 4, 256, 0, stream>>>(cw, conf, faT, fbT, wbb, tail);

    k_gemm1<<<(NPIX / 16) / 4, 256, 0, stream>>>(faT, wbb, tail, p1, hA, pbuf1);
    k_convgn<<<512, 256, 0, stream>>>(hA, g1, b1, pbuf1, p2, hB, pbuf2);
    k_convgn<<<512, 256, 0, stream>>>(hB, g2, b2, pbuf2, p3, hA, pbuf3);
    k_gnfinal<<<512, 256, 0, stream>>>(hA, g3, b3, pbuf3, cw, conf,
                                       dw, db, cwgt, cb, out);
}

// Round 17
// 122.319 us; speedup vs baseline: 1.5768x; 1.0009x over previous
//
#include <hip/hip_runtime.h>
#include <hip/hip_bf16.h>
#include <math.h>

#define B_ 2
#define H_ 128
#define W_ 128
#define C_ 256
#define HID 64
#define PIX_PER (H_*W_)          // 16384
#define NPIX (B_*PIX_PER)        // 32768
#define K1STEPS 25               // 800 / 32 (fa 0-7, wb 8-15, diff 16-23, tail 24)
#define K3STEPS 18               // 576 / 32
#define SROW 264                 // LDS tap-row stride in u16 (528B = 16B-aligned; do NOT shrink)
#define CTS 16                   // CT row stride in f32 (16B-aligned stores)

using f32x4 = __attribute__((ext_vector_type(4))) float;
using s16x8 = __attribute__((ext_vector_type(8))) short;
using u16x2 = __attribute__((ext_vector_type(2))) unsigned short;
using u16x4 = __attribute__((ext_vector_type(4))) unsigned short;
using u16x8 = __attribute__((ext_vector_type(8))) unsigned short;

__device__ __forceinline__ float bf2f(unsigned short u) {
    return __uint_as_float(((unsigned)u) << 16);
}
__device__ __forceinline__ unsigned short f2bf(float f) {
    unsigned u = __float_as_uint(f);
    u += 0x7FFFu + ((u >> 16) & 1u);
    return (unsigned short)(u >> 16);
}
__device__ __forceinline__ float clean15(float v) {
    if (v != v) v = 0.f;
    return fminf(fmaxf(v, -1.5f), 1.5f);
}
__device__ __forceinline__ float clean01(float v) {
    if (v != v) v = 0.f;
    return fminf(fmaxf(v, 0.f), 1.f);
}

// ---------------- transpose NCHW -> NHWC bf16 (+ weight pack on z==4) ----------------
__global__ __launch_bounds__(256) void k_transpose(const float* __restrict__ A,
                                                   const float* __restrict__ Bm,
                                                   unsigned short* __restrict__ faT,
                                                   unsigned short* __restrict__ fbT,
                                                   const float* __restrict__ w1,
                                                   const float* __restrict__ w2,
                                                   const float* __restrict__ w3,
                                                   unsigned short* __restrict__ p1,
                                                   unsigned short* __restrict__ p2,
                                                   unsigned short* __restrict__ p3)
{
    if (blockIdx.z == 4) {              // weight-pack slice
        if (blockIdx.y != 0 || blockIdx.x >= 61) return;
        int t = blockIdx.x * 256 + threadIdx.x;
        if (t < 6400) {                                   // enc1: 25 ksteps
            int lane = t & 63, nt = (t >> 6) & 3, ks = t >> 8;
            int n = nt * 16 + (lane & 15);
            int kb = ks * 32 + 8 * (lane >> 4);
#pragma unroll
            for (int j = 0; j < 8; j++) {
                int k = kb + j;
                p1[(size_t)t * 8 + j] = (k < 780) ? f2bf(w1[(size_t)n * 780 + k]) : (unsigned short)0;
            }
        } else if (t < 6400 + 2 * 4608) {                 // enc2/enc3: 18 ksteps each
            int which = (t - 6400) / 4608;
            int idx = (t - 6400) % 4608;
            const float* w = which ? w3 : w2;
            unsigned short* p = which ? p3 : p2;
            int lane = idx & 63, nt = (idx >> 6) & 3, ks = idx >> 8;
            int n = nt * 16 + (lane & 15);
            int tap = ks >> 1;
            int ky = tap / 3, kx = tap % 3;
#pragma unroll
            for (int j = 0; j < 8; j++) {
                int c = (ks & 1) * 32 + 8 * (lane >> 4) + j;
                p[(size_t)idx * 8 + j] = f2bf(w[(((size_t)n * 64 + c) * 3 + ky) * 3 + kx]);
            }
        }
        return;
    }
    __shared__ float tile[32][68];       // 272B rows: f32x4 stores stay aligned
    int hw0 = blockIdx.x * 64;
    int c0  = blockIdx.y * 32;
    int z   = blockIdx.z;                // b*2 + which
    int b   = z >> 1;
    const float* src = (z & 1) ? Bm : A;
    unsigned short* dst = (z & 1) ? fbT : faT;
    int tx = threadIdx.x & 15, ty = threadIdx.x >> 4;   // 16 x 16
    const float* s = src + ((size_t)b * C_ + c0) * (size_t)PIX_PER + hw0;
#pragma unroll
    for (int i = 0; i < 32; i += 16) {
        int c = ty + i;
        f32x4 v = *(const f32x4*)(s + (size_t)c * PIX_PER + tx * 4);
#pragma unroll
        for (int j = 0; j < 4; j++)
            if (!isfinite(v[j])) v[j] = 0.f;
        *(f32x4*)&tile[c][tx * 4] = v;
    }
    __syncthreads();
    unsigned short* d = dst + ((size_t)b * PIX_PER + hw0) * C_ + c0;
#pragma unroll
    for (int it = 0; it < 2; it++) {
        int idx = it * 256 + threadIdx.x;
        int pr = idx & 7;                 // channel quad (4pr+3 <= 31: in-block)
        int hw = idx >> 3;                // 0..63
        u16x4 o;
#pragma unroll
        for (int j = 0; j < 4; j++) o[j] = f2bf(tile[4 * pr + j][hw]);
        *(u16x4*)(d + (size_t)hw * C_ + 4 * pr) = o;
    }
}

// ---------------- sampling via per-pixel Gram MFMA, LDS-staged taps (r16, verified) ----------------
__global__ __launch_bounds__(256) void k_sample(const float* __restrict__ cw,
                                                const float* __restrict__ confp,
                                                const unsigned short* __restrict__ faT,
                                                const unsigned short* __restrict__ fbT,
                                                unsigned short* __restrict__ wbbuf,
                                                unsigned short* __restrict__ tail)
{
    __shared__ unsigned short S[4][17 * SROW];   // 35904 B: 16 taps + fa per wave
    __shared__ float CT[4][16 * CTS];            // 4096 B: Gram C^T per wave
    int lane = threadIdx.x & 63;
    int wv = threadIdx.x >> 6;
    int wid = blockIdx.x * 4 + wv;
    int b = wid >> 14, y = (wid >> 7) & 127, x = wid & 127;

    float gx = clean15(cw[(size_t)wid * 2 + 0]);
    float gy = clean15(cw[(size_t)wid * 2 + 1]);
    float conf = clean01(confp[wid]);

    float pxu = (gx + 1.f) * 64.f - 0.5f;
    float pyu = (gy + 1.f) * 64.f - 0.5f;
    float x0f = floorf(pxu), y0f = floorf(pyu);
    float wx = pxu - x0f, wy = pyu - y0f;
    int x0 = (int)x0f, y0 = (int)y0f;
    int co[4], ro[4];
#pragma unroll
    for (int k = 0; k < 4; k++) {
        co[k] = min(max(x0 - 1 + k, 0), 127) << 8;
        ro[k] = min(max(y0 - 1 + k, 0), 127) << 15;
    }
    const unsigned short* fbP = fbT + ((size_t)b << 22);

    // stage: issue all 9 coalesced loads first, then LDS writes
    int h = lane >> 5, lo = lane & 31;
    u16x8 stg[8];
#pragma unroll
    for (int i = 0; i < 8; i++) {
        int rr = ro[i >> 1];
        int cc = h ? co[((i & 1) << 1) + 1] : co[(i & 1) << 1];
        stg[i] = *(const u16x8*)(fbP + rr + cc + lo * 8);
    }
    u16x8 stfa;
    if (h == 0) stfa = *(const u16x8*)(faT + (size_t)wid * C_ + lo * 8);

    unsigned short* Sw = &S[wv][0];
#pragma unroll
    for (int i = 0; i < 8; i++)
        *(u16x8*)(Sw + (2 * i + h) * SROW + lo * 8) = stg[i];
    if (h == 0) *(u16x8*)(Sw + 16 * SROW + lo * 8) = stfa;

    // Gram via 8 MFMAs, fragments from LDS
    int q = lane & 15;
    int tA = (q == 0) ? 16 : q - 1;
    int koff = (lane >> 4) * 8;
    const unsigned short* pA = Sw + tA * SROW + koff;
    const unsigned short* pB = Sw + q * SROW + koff;
    f32x4 acc = {0.f, 0.f, 0.f, 0.f};
#pragma unroll
    for (int ks = 0; ks < 8; ks++) {
        s16x8 av = *(const s16x8*)(pA + ks * 32);
        s16x8 bv = *(const s16x8*)(pB + ks * 32);
        acc = __builtin_amdgcn_mfma_f32_16x16x32_bf16(av, bv, acc, 0, 0, 0);
    }
    *(f32x4*)&CT[wv][q * CTS + (lane >> 4) * 4] = acc;

    // wb (center bilerp) + fa^2 / t15^2 partials, all from LDS
    float w00 = (1.f - wx) * (1.f - wy), w01 = wx * (1.f - wy);
    float w10 = (1.f - wx) * wy,         w11 = wx * wy;
    u16x4 v5  = *(const u16x4*)(Sw + 5 * SROW + lane * 4);
    u16x4 v6  = *(const u16x4*)(Sw + 6 * SROW + lane * 4);
    u16x4 v9  = *(const u16x4*)(Sw + 9 * SROW + lane * 4);
    u16x4 v10 = *(const u16x4*)(Sw + 10 * SROW + lane * 4);
    u16x4 v15 = *(const u16x4*)(Sw + 15 * SROW + lane * 4);
    u16x4 vfa = *(const u16x4*)(Sw + 16 * SROW + lane * 4);
    float fa2p = 0.f, t152p = 0.f;
    u16x4 wbo;
#pragma unroll
    for (int i = 0; i < 4; i++) {
        float s = w00 * bf2f(v5[i]) + w01 * bf2f(v6[i])
                + w10 * bf2f(v9[i]) + w11 * bf2f(v10[i]);
        wbo[i] = f2bf(s);
        float fv = bf2f(vfa[i]), tv = bf2f(v15[i]);
        fa2p  += fv * fv;
        t152p += tv * tv;
    }
    *(u16x4*)(wbbuf + (size_t)wid * C_ + lane * 4) = wbo;
#pragma unroll
    for (int m = 1; m < 64; m <<= 1) {
        fa2p  += __shfl_xor(fa2p, m);
        t152p += __shfl_xor(t152p, m);
    }

    // epilogue: lanes 0..31 assemble the 32-entry tail row
    if (lane < 32) {
        float outv = 0.f;
        if (lane == 0)      outv = gx - (((float)x + 0.5f) * 0.015625f - 1.f);
        else if (lane == 1) outv = gy - (((float)y + 0.5f) * 0.015625f - 1.f);
        else if (lane == 2) outv = conf;
        else if (lane < 12) {
            int j = lane - 3;
            int jd = j / 3, jm = j - jd * 3;
            int m00 = jd * 4 + jm;
            const float* Cw = &CT[wv][0];
            float D00 = Cw[m00 * CTS], D01 = Cw[(m00 + 1) * CTS];
            float D10 = Cw[(m00 + 4) * CTS], D11 = Cw[(m00 + 5) * CTS];
            float dot = w00 * D00 + w01 * D01 + w10 * D10 + w11 * D11;
#define GR(a, b) Cw[(b) * CTS + (a) + 1]
            float g11 = (j == 8) ? t152p : GR(m00 + 5, m00 + 5);
            float s2 = w00 * w00 * GR(m00, m00) + w01 * w01 * GR(m00 + 1, m00 + 1)
                     + w10 * w10 * GR(m00 + 4, m00 + 4) + w11 * w11 * g11
                     + 2.f * (w00 * w01 * GR(m00, m00 + 1) + w00 * w10 * GR(m00, m00 + 4)
                            + w00 * w11 * GR(m00, m00 + 5) + w01 * w10 * GR(m00 + 1, m00 + 4)
                            + w01 * w11 * GR(m00 + 1, m00 + 5) + w10 * w11 * GR(m00 + 4, m00 + 5));
#undef GR
            outv = dot * rsqrtf(fmaxf(fa2p, 1e-24f)) * rsqrtf(fmaxf(s2, 1e-24f));
        }
        tail[(size_t)wid * 32 + lane] = f2bf(outv);
    }
}

// ---- GN partial-stats epilogue shared by gemm1/convgn (per-block partials) ----
__device__ __forceinline__ void gn_epilogue(const f32x4 acc[4], float* lds,
                                            float* __restrict__ pbuf, int bid,
                                            int la, int lb, int wv)
{
    int d = la >> 3;
    int slot = wv * 32 + lb * 8 + (la & 7);
#pragma unroll
    for (int nt = 0; nt < 4; nt++) {
        float s  = acc[nt][0] + acc[nt][1] + acc[nt][2] + acc[nt][3];
        float s2 = acc[nt][0] * acc[nt][0] + acc[nt][1] * acc[nt][1]
                 + acc[nt][2] * acc[nt][2] + acc[nt][3] * acc[nt][3];
        int g = nt * 2 + d;
        lds[(g * 128 + slot) * 2 + 0] = s;
        lds[(g * 128 + slot) * 2 + 1] = s2;
    }
    __syncthreads();
    int tid = threadIdx.x;
    int g = tid >> 5, i = tid & 31;
    float s  = lds[(g * 128 + i) * 2]     + lds[(g * 128 + i + 32) * 2]
             + lds[(g * 128 + i + 64) * 2] + lds[(g * 128 + i + 96) * 2];
    float s2 = lds[(g * 128 + i) * 2 + 1]     + lds[(g * 128 + i + 32) * 2 + 1]
             + lds[(g * 128 + i + 64) * 2 + 1] + lds[(g * 128 + i + 96) * 2 + 1];
#pragma unroll
    for (int m = 1; m < 32; m <<= 1) { s += __shfl_xor(s, m); s2 += __shfl_xor(s2, m); }
    if (i == 0) {
        pbuf[(bid * 8 + g) * 2]     = s;
        pbuf[(bid * 8 + g) * 2 + 1] = s2;
    }
}

// ------- conv1x1 as MFMA GEMM, single-pass A loads (fa+wb once, diff in-reg) -------
__global__ __launch_bounds__(256) void k_gemm1(const unsigned short* __restrict__ faT,
                                               const unsigned short* __restrict__ wbbuf,
                                               const unsigned short* __restrict__ tail,
                                               const unsigned short* __restrict__ pack,
                                               unsigned short* __restrict__ hpre,
                                               float* __restrict__ pbuf)
{
    __shared__ float lds[8 * 128 * 2];
    int wave = (blockIdx.x * 256 + threadIdx.x) >> 6;
    int lane = threadIdx.x & 63;
    int la = lane & 15, lb = lane >> 4;
    int row = wave * 16 + la;
    const unsigned short* fa_row = faT   + (size_t)row * C_ + lb * 8;
    const unsigned short* wb_row = wbbuf + (size_t)row * C_ + lb * 8;
    f32x4 acc[4] = {{0,0,0,0},{0,0,0,0},{0,0,0,0},{0,0,0,0}};

#pragma unroll
    for (int ks = 0; ks < 8; ks++) {
        u16x8 av = *(const u16x8*)(fa_row + ks * 32);
        u16x8 bv = *(const u16x8*)(wb_row + ks * 32);
        u16x8 dv;
#pragma unroll
        for (int j = 0; j < 8; j++)
            dv[j] = f2bf(fabsf(bf2f(av[j]) - bf2f(bv[j])));
        s16x8 fa_f = *(s16x8*)&av;
        s16x8 wb_f = *(s16x8*)&bv;
        s16x8 df_f = *(s16x8*)&dv;
#pragma unroll
        for (int nt = 0; nt < 4; nt++) {
            acc[nt] = __builtin_amdgcn_mfma_f32_16x16x32_bf16(fa_f,
                *(const s16x8*)(pack + ((size_t)(ks * 4 + nt) * 64 + lane) * 8), acc[nt], 0, 0, 0);
            acc[nt] = __builtin_amdgcn_mfma_f32_16x16x32_bf16(wb_f,
                *(const s16x8*)(pack + ((size_t)((ks + 8) * 4 + nt) * 64 + lane) * 8), acc[nt], 0, 0, 0);
            acc[nt] = __builtin_amdgcn_mfma_f32_16x16x32_bf16(df_f,
                *(const s16x8*)(pack + ((size_t)((ks + 16) * 4 + nt) * 64 + lane) * 8), acc[nt], 0, 0, 0);
        }
    }
    {
        s16x8 a = *(const s16x8*)(tail + (size_t)row * 32 + lb * 8);
#pragma unroll
        for (int nt = 0; nt < 4; nt++)
            acc[nt] = __builtin_amdgcn_mfma_f32_16x16x32_bf16(a,
                *(const s16x8*)(pack + ((size_t)(24 * 4 + nt) * 64 + lane) * 8), acc[nt], 0, 0, 0);
    }

    int orow = wave * 16 + lb * 4;
#pragma unroll
    for (int nt = 0; nt < 4; nt++)
#pragma unroll
        for (int r = 0; r < 4; r++)
            hpre[(size_t)(orow + r) * HID + nt * 16 + la] = f2bf(acc[nt][r]);

    gn_epilogue(acc, lds, pbuf, blockIdx.x, la, lb, (threadIdx.x >> 6));
}

// ------- fused GN + GELU + conv3x3 (r12-verified): 8x8 tile per block -------
__global__ __launch_bounds__(256) void k_convgn(const unsigned short* __restrict__ hin,
                                                const float* __restrict__ gamma,
                                                const float* __restrict__ beta,
                                                const float* __restrict__ pbin,
                                                const unsigned short* __restrict__ pack,
                                                unsigned short* __restrict__ hout,
                                                float* __restrict__ pbout)
{
    __shared__ unsigned short T[8 * 100 * 8];   // [c8][py*10+px][8ch] = 12800 B
    __shared__ float eplds[8 * 128 * 2];        // 8 KB
    __shared__ float sm[16];
    int tid = threadIdx.x;
    int bid = blockIdx.x;                        // 512 = 2 batches x 16x16 tiles
    int b = bid >> 8;
    int tile = bid & 255;
    int ty0 = (tile >> 4) << 3, tx0 = (tile & 15) << 3;

    // fold prev-layer GN stats (256 partial-blocks per batch)
    {
        int g = tid >> 5, i = tid & 31;
        float s = 0.f, s2 = 0.f;
#pragma unroll
        for (int k = 0; k < 8; k++) {
            int pb = b * 256 + i + k * 32;
            s  += pbin[(pb * 8 + g) * 2];
            s2 += pbin[(pb * 8 + g) * 2 + 1];
        }
#pragma unroll
        for (int m = 1; m < 32; m <<= 1) { s += __shfl_xor(s, m); s2 += __shfl_xor(s2, m); }
        if (i == 0) {
            const float inv = 1.f / 131072.f;
            float mean = s * inv;
            float var = fmaxf(s2 * inv - mean * mean, 0.f);
            sm[g * 2] = mean;
            sm[g * 2 + 1] = rsqrtf(var + 1e-5f);
        }
    }
    __syncthreads();

    // stage 10x10 halo with GN+GELU: 100 slots x 8 ch-octets = 800 tasks
#pragma unroll
    for (int pass = 0; pass < 4; pass++) {
        int idx = pass * 256 + tid;
        if (idx < 800) {
            int c8 = idx & 7, slot = idx >> 3;
            int py = slot / 10, px = slot - py * 10;
            int gy = ty0 + py - 1, gx = tx0 + px - 1;
            u16x8 o = {0, 0, 0, 0, 0, 0, 0, 0};
            if ((unsigned)gy < 128u && (unsigned)gx < 128u) {
                int gpix = (b << 14) + (gy << 7) + gx;
                u16x8 v = *(const u16x8*)(hin + (size_t)gpix * HID + c8 * 8);
                float mean = sm[c8 * 2], rstd = sm[c8 * 2 + 1];
#pragma unroll
                for (int i = 0; i < 8; i++) {
                    int c = c8 * 8 + i;
                    float xn = (bf2f(v[i]) - mean) * rstd * gamma[c] + beta[c];
                    o[i] = f2bf(0.5f * xn * (1.f + erff(xn * 0.70710678118654752f)));
                }
            }
            *(u16x8*)(&T[(c8 * 100 + slot) * 8]) = o;
        }
    }
    __syncthreads();

    // conv3x3: wave wv -> output rows {2wv, 2wv+1} of the 8x8 tile
    int lane = tid & 63, wv = tid >> 6;
    int la = lane & 15, lb = lane >> 4;
    int ay = la >> 3, ax = la & 7;              // A-row la -> (row-pair offset, x)
    f32x4 acc[4] = {{0,0,0,0},{0,0,0,0},{0,0,0,0},{0,0,0,0}};
#pragma unroll
    for (int ks = 0; ks < K3STEPS; ks++) {
        int tap = ks >> 1;
        int dy = tap / 3, dx = tap - dy * 3;
        int c8 = (ks & 1) * 4 + lb;
        int py = wv * 2 + ay + dy;
        int px = ax + dx;
        s16x8 a = *(const s16x8*)(&T[(c8 * 100 + py * 10 + px) * 8]);
#pragma unroll
        for (int nt = 0; nt < 4; nt++)
            acc[nt] = __builtin_amdgcn_mfma_f32_16x16x32_bf16(a,
                *(const s16x8*)(pack + ((size_t)(ks * 4 + nt) * 64 + lane) * 8), acc[nt], 0, 0, 0);
    }

    // write pre-GN output: C row = px_off = lb*4+r -> (y = +po>>3, x = po&7)
#pragma unroll
    for (int nt = 0; nt < 4; nt++)
#pragma unroll
        for (int r = 0; r < 4; r++) {
            int po = lb * 4 + r;
            int yy = ty0 + wv * 2 + (po >> 3);
            int xx = tx0 + (po & 7);
            hout[((size_t)((b << 14) + (yy << 7) + xx)) * HID + nt * 16 + la] = f2bf(acc[nt][r]);
        }

    gn_epilogue(acc, eplds, pbout, bid, la, lb, wv);
}

// ------- fused GN3 + GELU + delta/conf heads + epilogue (verified r11) -------
__global__ __launch_bounds__(256) void k_gnfinal(const unsigned short* __restrict__ hpre,
                                                 const float* __restrict__ gamma,
                                                 const float* __restrict__ beta,
                                                 const float* __restrict__ pbuf,
                                                 const float* __restrict__ cw,
                                                 const float* __restrict__ confp,
                                                 const float* __restrict__ dw,
                                                 const float* __restrict__ db,
                                                 const float* __restrict__ cwgt,
                                                 const float* __restrict__ cb,
                                                 float* __restrict__ out)
{
    __shared__ unsigned short hnT[100 * 68];   // 10x10 px, 64 ch + 4 pad (13.6 KB)
    __shared__ float wds[1154];
    __shared__ float wcs[577];
    __shared__ float sm[16];
    int tid = threadIdx.x;
    int bid = blockIdx.x;                       // 512 = 2 batches x 16x16 tiles
    int b = bid >> 8;
    int tile = bid & 255;
    int ty0 = (tile >> 4) << 3, tx0 = (tile & 15) << 3;

    for (int i = tid; i < 1152; i += 256) wds[i] = dw[i];
    for (int i = tid; i < 576; i += 256) wcs[i] = cwgt[i];
    if (tid == 0) { wds[1152] = db[0]; wds[1153] = db[1]; wcs[576] = cb[0]; }

    // GN stats fold (256 convgn-blocks per batch)
    {
        int g = tid >> 5, i = tid & 31;
        float s = 0.f, s2 = 0.f;
#pragma unroll
        for (int k = 0; k < 8; k++) {
            int pb = b * 256 + i + k * 32;
            s  += pbuf[(pb * 8 + g) * 2];
            s2 += pbuf[(pb * 8 + g) * 2 + 1];
        }
#pragma unroll
        for (int m = 1; m < 32; m <<= 1) { s += __shfl_xor(s, m); s2 += __shfl_xor(s2, m); }
        if (i == 0) {
            const float inv = 1.f / 131072.f;
            float mean = s * inv;
            float var = fmaxf(s2 * inv - mean * mean, 0.f);
            sm[g * 2] = mean;
            sm[g * 2 + 1] = rsqrtf(var + 1e-5f);
        }
    }
    __syncthreads();

    // load halo + GN + GELU into LDS: 100 slots x 8 ch-octets = 800 items
#pragma unroll
    for (int pass = 0; pass < 4; pass++) {
        int idx = pass * 256 + tid;
        if (idx < 800) {
            int slot = idx >> 3, c8 = idx & 7;
            int py = slot / 10, px = slot - py * 10;
            int gy = ty0 + py - 1, gx = tx0 + px - 1;
            u16x8 o = {0, 0, 0, 0, 0, 0, 0, 0};
            if ((unsigned)gy < 128u && (unsigned)gx < 128u) {
                int gpix = (b << 14) + (gy << 7) + gx;
                u16x8 v = *(const u16x8*)(hpre + (size_t)gpix * HID + c8 * 8);
                float mean = sm[c8 * 2], rstd = sm[c8 * 2 + 1];
#pragma unroll
                for (int i = 0; i < 8; i++) {
                    int c = c8 * 8 + i;
                    float xn = (bf2f(v[i]) - mean) * rstd * gamma[c] + beta[c];
                    float ge = 0.5f * xn * (1.f + erff(xn * 0.70710678118654752f));
                    o[i] = f2bf(ge);
                }
            }
            *(u16x8*)(&hnT[slot * 68 + c8 * 8]) = o;
        }
    }
    __syncthreads();

    // heads: px p = tid>>2 (8x8 interior), part = tid&3 (2 ch-octets each)
    int p = tid >> 2, part = tid & 3;
    int py = (p >> 3) + 1, px = (p & 7) + 1;
    float d0 = 0.f, d1 = 0.f, c0 = 0.f;
#pragma unroll
    for (int ky = 0; ky < 3; ky++)
#pragma unroll
        for (int kx = 0; kx < 3; kx++) {
            const unsigned short* hp = &hnT[((py + ky - 1) * 10 + (px + kx - 1)) * 68];
            int widx = ky * 3 + kx;
#pragma unroll
            for (int cc = 0; cc < 2; cc++) {
                int c8 = part * 2 + cc;
                u16x8 v = *(const u16x8*)(hp + c8 * 8);
#pragma unroll
                for (int i = 0; i < 8; i++) {
                    float f = bf2f(v[i]);
                    int c = c8 * 8 + i;
                    d0 += f * wds[c * 9 + widx];
                    d1 += f * wds[576 + c * 9 + widx];
                    c0 += f * wcs[c * 9 + widx];
                }
            }
        }
#pragma unroll
    for (int m = 1; m < 4; m <<= 1) {
        d0 += __shfl_xor(d0, m);
        d1 += __shfl_xor(d1, m);
        c0 += __shfl_xor(c0, m);
    }
    if (part == 0) {
        int pix = (b << 14) + ((ty0 + py - 1) << 7) + (tx0 + px - 1);
        d0 = tanhf(d0 + wds[1152]);
        d1 = tanhf(d1 + wds[1153]);
        c0 += wcs[576];

        float gx = clean15(cw[(size_t)pix * 2 + 0]);
        float gy = clean15(cw[(size_t)pix * 2 + 1]);
        float fwx = fminf(fmaxf(gx + d0 * 0.0625f, -1.5f), 1.5f);
        float fwy = fminf(fmaxf(gy + d1 * 0.0625f, -1.5f), 1.5f);

        float conf = clean01(confp[pix]);
        float pp = fminf(fmaxf(conf, 1e-4f), 1.f - 1e-4f);
        float bl = logf(pp) - log1pf(-pp);
        float rl = bl + 0.5f * c0;
        float rc = fminf(fmaxf(1.f / (1.f + expf(-rl)), 0.f), 1.f);

        out[(size_t)pix * 2 + 0] = fwx;
        out[(size_t)pix * 2 + 1] = fwy;
        out[(size_t)NPIX * 2 + pix] = rc;
        out[(size_t)NPIX * 2 + NPIX + pix] = rl;
    }
}

// ---------------- launcher ----------------
extern "C" void kernel_launch(void* const* d_in, const int* in_sizes, int n_in,
                              void* d_out, int out_size, void* d_ws, size_t ws_size,
                              hipStream_t stream)
{
    const float* feat_A = (const float*)d_in[0];
    const float* feat_B = (const float*)d_in[1];
    const float* cw     = (const float*)d_in[2];
    const float* conf   = (const float*)d_in[3];
    const float* w1     = (const float*)d_in[4];
    const float* g1     = (const float*)d_in[5];
    const float* b1     = (const float*)d_in[6];
    const float* w2     = (const float*)d_in[7];
    const float* g2     = (const float*)d_in[8];
    const float* b2     = (const float*)d_in[9];
    const float* w3     = (const float*)d_in[10];
    const float* g3     = (const float*)d_in[11];
    const float* b3     = (const float*)d_in[12];
    const float* dw     = (const float*)d_in[13];
    const float* db     = (const float*)d_in[14];
    const float* cwgt   = (const float*)d_in[15];
    const float* cb     = (const float*)d_in[16];
    float* out = (float*)d_out;

    char* w = (char*)d_ws;
    size_t o = 0;
    unsigned short* faT  = (unsigned short*)(w + o); o += (size_t)NPIX * C_ * 2;     // 16 MB
    unsigned short* fbT  = (unsigned short*)(w + o); o += (size_t)NPIX * C_ * 2;     // 16 MB
    unsigned short* wbb  = (unsigned short*)(w + o); o += (size_t)NPIX * C_ * 2;     // 16 MB
    unsigned short* tail = (unsigned short*)(w + o); o += (size_t)NPIX * 32 * 2;     // 2 MB
    unsigned short* hA   = (unsigned short*)(w + o); o += (size_t)NPIX * HID * 2;    // 4 MB
    unsigned short* hB   = (unsigned short*)(w + o); o += (size_t)NPIX * HID * 2;    // 4 MB
    unsigned short* p1   = (unsigned short*)(w + o); o += (size_t)K1STEPS * 4 * 64 * 8 * 2;
    unsigned short* p2   = (unsigned short*)(w + o); o += (size_t)K3STEPS * 4 * 64 * 8 * 2;
    unsigned short* p3   = (unsigned short*)(w + o); o += (size_t)K3STEPS * 4 * 64 * 8 * 2;
    float* pbuf1 = (float*)(w + o); o += 512 * 8 * 2 * 4;
    float* pbuf2 = (float*)(w + o); o += 512 * 8 * 2 * 4;
    float* pbuf3 = (float*)(w + o); o += 512 * 8 * 2 * 4;

    k_transpose<<<dim3(PIX_PER / 64, C_ / 32, 5), 256, 0, stream>>>(feat_A, feat_B, faT, fbT,
                                                                    w1, w2, w3, p1, p2, p3);
    k_sample<<<NPIX / 4, 256, 0, stream>>>(cw, conf, faT, fbT, wbb, tail);

    k_gemm1<<<(NPIX / 16) / 4, 256, 0, stream>>>(faT, wbb, tail, p1, hA, pbuf1);
    k_convgn<<<512, 256, 0, stream>>>(hA, g1, b1, pbuf1, p2, hB, pbuf2);
    k_convgn<<<512, 256, 0, stream>>>(hB, g2, b2, pbuf2, p3, hA, pbuf3);
    k_gnfinal<<<512, 256, 0, stream>>>(hA, g3, b3, pbuf3, cw, conf,
                                       dw, db, cwgt, cb, out);
}